// Round 16
// baseline (146.983 us; speedup 1.0000x reference)
//
#include <hip/hip_runtime.h>
#include <hip/hip_bf16.h>

#define D_DIM 256
#define NPG   256
#define HEADS 4
#define HD    64
#define BCAP  64   // per-node edge bucket capacity (deg ~ Poisson(16))

typedef __bf16 bf16x8 __attribute__((ext_vector_type(8)));
typedef __bf16 bf16x4 __attribute__((ext_vector_type(4)));
typedef float  f32x4  __attribute__((ext_vector_type(4)));

__device__ inline float us2f(unsigned short u) {
    union { unsigned int i; float f; } cv; cv.i = ((unsigned int)u) << 16; return cv.f;
}

// async global->LDS, 16B per lane (dest = wave-uniform base + lane*16)
#define GLOAD_LDS16(g, l) __builtin_amdgcn_global_load_lds(                    \
    (const __attribute__((address_space(1))) void*)(g),                        \
    (__attribute__((address_space(3))) void*)(l), 16, 0, 0)

// ---------------------------------------------------------------------------
// merged prep: [0,nb1) convert_pack_x | [nb1,nb1+128) transpose_pack_w8 |
//              [nb1+128, ...) zero deg
__global__ __launch_bounds__(256) void prep_misc(const float* __restrict__ x,
                                                 __bf16* __restrict__ xpk,
        const float* w0, const float* w1, const float* w2, const float* w3,
        const float* w4, const float* w5, const float* w6, const float* w7,
        __bf16* __restrict__ wt, int* __restrict__ zeros, int nb1, int tot) {
    __shared__ __bf16 tile[256][16];
    int bid = blockIdx.x;
    const int t = threadIdx.x;
    if (bid < nb1) {
        const int rt = bid;
        const int ks = t >> 5;
        #pragma unroll
        for (int h2 = 0; h2 < 2; ++h2) {
            int lane = (t & 31) * 2 + h2;
            int row = rt * 16 + (lane & 15);
            int col = ks * 32 + (lane >> 4) * 8;
            const float4* src = reinterpret_cast<const float4*>(x + (size_t)row * 256 + col);
            float4 f0 = src[0], f1 = src[1];
            __bf16* o = xpk + ((size_t)(rt * 8 + ks) * 64 + lane) * 8;
            o[0] = (__bf16)f0.x; o[1] = (__bf16)f0.y; o[2] = (__bf16)f0.z; o[3] = (__bf16)f0.w;
            o[4] = (__bf16)f1.x; o[5] = (__bf16)f1.y; o[6] = (__bf16)f1.z; o[7] = (__bf16)f1.w;
        }
        return;
    }
    bid -= nb1;
    if (bid < 128) {
        const float* Ws[8] = {w0, w1, w2, w3, w4, w5, w6, w7};
        const int jt2 = bid & 15, wsel = bid >> 4;
        const float* W = Ws[wsel];
        const float4* wr = reinterpret_cast<const float4*>(W + (size_t)t * 256 + jt2 * 16);
        #pragma unroll
        for (int u = 0; u < 4; ++u) {
            float4 f = wr[u];
            tile[t][u * 4 + 0] = (__bf16)f.x; tile[t][u * 4 + 1] = (__bf16)f.y;
            tile[t][u * 4 + 2] = (__bf16)f.z; tile[t][u * 4 + 3] = (__bf16)f.w;
        }
        __syncthreads();
        __bf16* out = wt + ((size_t)wsel * 16 + jt2) * 4096;
        #pragma unroll
        for (int u = 0; u < 16; ++u) {
            int e = t * 16 + u;
            int ks = e >> 9, lane = (e >> 3) & 63, i = e & 7;
            int g = lane >> 4, c = lane & 15;
            int k = ks * 32 + g * 8 + i;
            out[e] = tile[k][c];
        }
        return;
    }
    bid -= 128;
    int i = bid * 256 + t;
    if (i < tot) zeros[i] = 0;
}

// ---------------------------------------------------------------------------
// Fused: 7-projection GEMM (blocks [0,nb_gemm)) + edge-bucket build (rest).
// XCD-swizzled: XCD k owns row-chunks x in [8k, 8k+8) for ALL 28 y values,
// so each XCD's A working set is 1MB (L2-resident). 8 A-loads in flight per
// wave (launch_bounds(512,4) -> <=128 VGPR).
__global__ __launch_bounds__(512, 4) void proj_csr(const __bf16* __restrict__ xpk,
                                                   const __bf16* __restrict__ wt,
        const float* b_gq, const float* b_gk, const float* b_gv,
        const float* b_lq, const float* b_lk, const float* b_lv, const float* b_ls,
        __bf16* o_gq, __bf16* o_gk, __bf16* Vt,
        __bf16* o_lq, __bf16* o_lk, __bf16* o_lv, __bf16* o_ls,
        const int* __restrict__ ei_raw, int* __restrict__ bucket,
        int* __restrict__ deg, int E, int nb_gemm, int M) {
    __shared__ __align__(16) __bf16 wlds[16384];   // one packed W quarter (32KB)
    int bid = blockIdx.x;
    if (bid >= nb_gemm) {
        // ---- edge part: dtype detect + bucket scatter ----
        int v = ei_raw[2 * (threadIdx.x & 63) + 1];
        unsigned long long nz = __ballot(v != 0);
        bool is64 = (nz == 0ULL);
        int e = (bid - nb_gemm) * 512 + threadIdx.x;
        if (e >= E) return;
        int s, d;
        if (is64) { s = ei_raw[2 * e]; d = ei_raw[2 * (E + e)]; }
        else      { s = ei_raw[e];     d = ei_raw[E + e]; }
        int p = atomicAdd(&deg[d], 1);
        if (p < BCAP) bucket[d * BCAP + p] = s;
        return;
    }
    const int gx = M >> 8;            // row-blocks (256 rows each); must be %8==0
    const int chunk = gx >> 3;        // x's per XCD
    const int xcd = bid & 7;
    const int local = bid >> 3;       // [0, nb_gemm/8)
    const int x = xcd * chunk + (local % chunk);
    const int y = local / chunk;
    const int j = y >> 2;
    const int q = y & 3;
    const int wsel = (j < 3) ? j : j + 1;
    const float* bias = (j == 0) ? b_gq : (j == 1) ? b_gk : (j == 2) ? b_gv :
                        (j == 3) ? b_lq : (j == 4) ? b_lk : (j == 5) ? b_lv : b_ls;
    __bf16* C = (j == 0) ? o_gq : (j == 1) ? o_gk : (j == 2) ? nullptr :
                (j == 3) ? o_lq : (j == 4) ? o_lk : (j == 5) ? o_lv : o_ls;

    // async stage of the 32KB packed-W quarter (linear LDS, 16B/lane)
    {
        const __bf16* gs = wt + (size_t)wsel * 65536 + (size_t)q * 16384;
        #pragma unroll
        for (int it = 0; it < 4; ++it) {
            int ch = it * 512 + threadIdx.x;
            GLOAD_LDS16(gs + ch * 8, wlds + ch * 8);
        }
    }

    const int wid = threadIdx.x >> 6, lane = threadIdx.x & 63;
    const int g = lane >> 4, c = lane & 15;
    const int rt0 = x * 16 + wid * 2;
    const char* wl = reinterpret_cast<const char*>(wlds) + lane * 16;

    // h=0: issue ALL 8 A-frag loads before the barrier (overlap W stage)
    const __bf16* ap0 = xpk + ((size_t)rt0 * 8) * 512 + lane * 8;
    bf16x8 af[8];
    #pragma unroll
    for (int ks = 0; ks < 8; ++ks)
        af[ks] = *reinterpret_cast<const bf16x8*>(ap0 + ks * 512);

    __syncthreads();   // drains gload_lds (vmcnt) + orders LDS

    #pragma unroll
    for (int h = 0; h < 2; ++h) {
        f32x4 acc[4];
        #pragma unroll
        for (int jt = 0; jt < 4; ++jt) acc[jt] = (f32x4){0.f, 0.f, 0.f, 0.f};
        #pragma unroll
        for (int ks = 0; ks < 8; ++ks) {
            #pragma unroll
            for (int jt = 0; jt < 4; ++jt) {
                bf16x8 bf_ = *reinterpret_cast<const bf16x8*>(wl + (jt * 8 + ks) * 1024);
                acc[jt] = __builtin_amdgcn_mfma_f32_16x16x32_bf16(bf_, af[ks], acc[jt], 0, 0, 0);
            }
            if (h == 0) {   // prefetch h=1's A-frag while computing h=0
                const __bf16* ap1 = xpk + ((size_t)(rt0 + 1) * 8) * 512 + lane * 8;
                af[ks] = *reinterpret_cast<const bf16x8*>(ap1 + ks * 512);
            }
        }
        // epilogue for this h
        if (j == 2) {
            int m = (rt0 + h) * 16 + c;
            int b = m >> 8, mm = m & 255;
            #pragma unroll
            for (int jt = 0; jt < 4; ++jt) {
                int col0 = q * 64 + jt * 16 + g * 4;
                float4 bv = *reinterpret_cast<const float4*>(bias + col0);
                Vt[(size_t)(b * 256 + col0 + 0) * 256 + mm] = (__bf16)(acc[jt][0] + bv.x);
                Vt[(size_t)(b * 256 + col0 + 1) * 256 + mm] = (__bf16)(acc[jt][1] + bv.y);
                Vt[(size_t)(b * 256 + col0 + 2) * 256 + mm] = (__bf16)(acc[jt][2] + bv.z);
                Vt[(size_t)(b * 256 + col0 + 3) * 256 + mm] = (__bf16)(acc[jt][3] + bv.w);
            }
        } else {
            int row = (rt0 + h) * 16 + c;
            #pragma unroll
            for (int jt = 0; jt < 4; ++jt) {
                int col0 = q * 64 + jt * 16 + g * 4;
                float4 bv = *reinterpret_cast<const float4*>(bias + col0);
                bf16x4 st;
                st[0] = (__bf16)(acc[jt][0] + bv.x);
                st[1] = (__bf16)(acc[jt][1] + bv.y);
                st[2] = (__bf16)(acc[jt][2] + bv.z);
                st[3] = (__bf16)(acc[jt][3] + bv.w);
                *reinterpret_cast<bf16x4*>(&C[(size_t)row * 256 + col0]) = st;
            }
        }
    }
}

// ---------------------------------------------------------------------------
// go GEMM: 32KB W quarter staged async into LDS. Wave 16 rows x 64 cols.
__global__ __launch_bounds__(256) void gemm_go(const __bf16* __restrict__ A,
                                               const __bf16* __restrict__ Wp,
                                               const float* __restrict__ bias,
                                               __bf16* __restrict__ C, int M) {
    __shared__ __align__(16) __bf16 wlds[16384];
    {
        const __bf16* gs = Wp + (size_t)blockIdx.y * 16384;
        #pragma unroll
        for (int it = 0; it < 8; ++it) {
            int chunk = it * 256 + threadIdx.x;
            GLOAD_LDS16(gs + chunk * 8, wlds + chunk * 8);
        }
    }
    const int wid = threadIdx.x >> 6, lane = threadIdx.x & 63;
    const int g = lane >> 4, c = lane & 15;
    const int row0 = blockIdx.x * 64 + wid * 16;

    const __bf16* arow = A + (size_t)(row0 + c) * 256 + g * 8;
    bf16x8 af = *reinterpret_cast<const bf16x8*>(arow);   // prefetch before barrier

    f32x4 acc[4];
    #pragma unroll
    for (int jt = 0; jt < 4; ++jt) acc[jt] = (f32x4){0.f, 0.f, 0.f, 0.f};

    const char* wl = reinterpret_cast<const char*>(wlds) + lane * 16;
    __syncthreads();
    #pragma unroll
    for (int ks = 0; ks < 8; ++ks) {
        bf16x8 nf;
        if (ks < 7) nf = *reinterpret_cast<const bf16x8*>(arow + (ks + 1) * 32);
        #pragma unroll
        for (int jt = 0; jt < 4; ++jt) {
            bf16x8 bf_ = *reinterpret_cast<const bf16x8*>(wl + (jt * 8 + ks) * 1024);
            acc[jt] = __builtin_amdgcn_mfma_f32_16x16x32_bf16(bf_, af, acc[jt], 0, 0, 0);
        }
        af = nf;
    }
    int row = row0 + c;
    #pragma unroll
    for (int jt = 0; jt < 4; ++jt) {
        int col0 = blockIdx.y * 64 + jt * 16 + g * 4;
        float4 bv = *reinterpret_cast<const float4*>(bias + col0);
        bf16x4 st;
        st[0] = (__bf16)(acc[jt][0] + bv.x);
        st[1] = (__bf16)(acc[jt][1] + bv.y);
        st[2] = (__bf16)(acc[jt][2] + bv.z);
        st[3] = (__bf16)(acc[jt][3] + bv.w);
        *reinterpret_cast<bf16x4*>(&C[(size_t)row * 256 + col0]) = st;
    }
}

// ---------------------------------------------------------------------------
// local attention: wave per node, 4 edges in parallel, src from bucket; bf16 out.
__global__ __launch_bounds__(256) void local_attn_bf16(const __bf16* __restrict__ q,
                                                       const __bf16* __restrict__ k,
                                                       const __bf16* __restrict__ v,
                                                       const int* __restrict__ bucket,
                                                       const int* __restrict__ deg,
                                                       __bf16* __restrict__ aggb, int tot) {
    int bid = blockIdx.x;
    bid = (bid & 7) * (gridDim.x >> 3) + (bid >> 3);   // XCD-contiguous chunks
    int w = (bid * 256 + (int)threadIdx.x) >> 6;
    int lane = threadIdx.x & 63;
    if (w >= tot) return;
    const int t = w;
    const int g = lane >> 4, cc = lane & 15;

    float qf[16];
    {
        const ushort4* qr = reinterpret_cast<const ushort4*>(q + (size_t)t * 256);
        #pragma unroll
        for (int u = 0; u < 4; ++u) {
            ushort4 qv = qr[cc * 4 + u];
            qf[u * 4 + 0] = us2f(qv.x); qf[u * 4 + 1] = us2f(qv.y);
            qf[u * 4 + 2] = us2f(qv.z); qf[u * 4 + 3] = us2f(qv.w);
        }
    }

    int dg = deg[t];
    if (dg > BCAP) dg = BCAP;
    const int* bkt = bucket + (size_t)t * BCAP;
    float M = -3.0e38f, den = 0.f;
    float a0 = 0.f, a1 = 0.f, a2 = 0.f, a3 = 0.f;

    for (int i0 = 0; i0 < dg; i0 += 4) {
        bool valid = (i0 + g) < dg;
        int s = valid ? bkt[i0 + g] : 0;

        float p = 0.f;
        const ushort4* kr = reinterpret_cast<const ushort4*>(k + (size_t)s * 256);
        #pragma unroll
        for (int u = 0; u < 4; ++u) {
            ushort4 kv = kr[cc * 4 + u];
            p += qf[u * 4 + 0] * us2f(kv.x) + qf[u * 4 + 1] * us2f(kv.y)
               + qf[u * 4 + 2] * us2f(kv.z) + qf[u * 4 + 3] * us2f(kv.w);
        }
        p += __shfl_xor(p, 1); p += __shfl_xor(p, 2);
        p += __shfl_xor(p, 4); p += __shfl_xor(p, 8);

        float lg[4]; int sj[4];
        #pragma unroll
        for (int j = 0; j < 4; ++j) {
            float pj = __shfl(p, j * 16);
            int   ssj = __shfl(s, j * 16);
            bool vj = (i0 + j) < dg;
            lg[j] = vj ? pj * 0.0625f : -3.0e38f;
            sj[j] = vj ? ssj : 0;
        }

        float nM = fmaxf(fmaxf(fmaxf(lg[0], lg[1]), fmaxf(lg[2], lg[3])), M);
        float sc = __expf(M - nM);
        float ex[4];
        #pragma unroll
        for (int j = 0; j < 4; ++j) ex[j] = __expf(lg[j] - nM);

        float s0 = 0.f, s1 = 0.f, s2 = 0.f, s3 = 0.f;
        #pragma unroll
        for (int j = 0; j < 4; ++j) {
            ushort4 vv = reinterpret_cast<const ushort4*>(v + (size_t)sj[j] * 256)[lane];
            s0 += ex[j] * us2f(vv.x); s1 += ex[j] * us2f(vv.y);
            s2 += ex[j] * us2f(vv.z); s3 += ex[j] * us2f(vv.w);
        }
        a0 = a0 * sc + s0; a1 = a1 * sc + s1;
        a2 = a2 * sc + s2; a3 = a3 * sc + s3;
        den = den * sc + ex[0] + ex[1] + ex[2] + ex[3];
        M = nM;
    }
    float inv = (dg > 0) ? 1.0f / den : 0.0f;
    bf16x4 o;
    o[0] = (__bf16)(a0 * inv); o[1] = (__bf16)(a1 * inv);
    o[2] = (__bf16)(a2 * inv); o[3] = (__bf16)(a3 * inv);
    reinterpret_cast<bf16x4*>(aggb + (size_t)t * 256)[lane] = o;
}

// ---------------------------------------------------------------------------
// MFMA global attention: K and V both staged in LDS (swizzled); P overlays K.
__global__ __launch_bounds__(256) void global_attn_mfma(const __bf16* __restrict__ Qb,
                                                        const __bf16* __restrict__ Kb,
                                                        const __bf16* __restrict__ Vt,
                                                        __bf16* __restrict__ od) {
    __shared__ __align__(16) char lds[65536];   // [0,32K): K then P; [32K,64K): V
    const int tid = threadIdx.x;
    const int wid = tid >> 6, lane = tid & 63;
    const int bh = blockIdx.x >> 2, qq = blockIdx.x & 3;
    const int b = bh >> 2, h = bh & 3;
    const int qb = qq * 4 + wid;
    const int g = lane >> 4, c = lane & 15;

    // ---- stage K slice (32KB) ----
    {
        const __bf16* kgp = Kb + ((size_t)b * 256) * 256 + h * 64;
        int krow = tid >> 3, ch = tid & 7;
        #pragma unroll
        for (int p = 0; p < 8; ++p) {
            int kk = p * 32 + krow;
            bf16x8 val = *reinterpret_cast<const bf16x8*>(kgp + (size_t)kk * 256 + ch * 8);
            int bo = (kk * 128 + ch * 16) ^ ((kk & 7) << 4);
            *reinterpret_cast<bf16x8*>(lds + bo) = val;
        }
    }
    // ---- stage V slice (32KB), row-major [64][256], swizzled ----
    {
        const bf16x8* vgp = reinterpret_cast<const bf16x8*>(Vt + (size_t)bh * 16384);
        #pragma unroll
        for (int p = 0; p < 8; ++p) {
            int off = p * 256 + tid;            // 16B chunk index
            bf16x8 val = vgp[off];
            int row = off >> 5;
            int colb = (off & 31) * 16;
            int bo = 32768 + ((row * 512 + colb) ^ ((row & 7) << 4));
            *reinterpret_cast<bf16x8*>(lds + bo) = val;
        }
    }
    const __bf16* qptr = Qb + ((size_t)(b * 256 + qb * 16 + c)) * 256 + h * 64 + g * 8;
    bf16x8 aq0 = *reinterpret_cast<const bf16x8*>(qptr);
    bf16x8 aq1 = *reinterpret_cast<const bf16x8*>(qptr + 32);
    __syncthreads();

    // ---- QK^T from LDS ----
    f32x4 S[16];
    #pragma unroll
    for (int jt = 0; jt < 16; ++jt) S[jt] = (f32x4){0.f, 0.f, 0.f, 0.f};
    #pragma unroll
    for (int jt = 0; jt < 16; ++jt) {
        int key = jt * 16 + c;
        int sw = (key & 7) << 4;
        int bo0 = (key * 128 + g * 16) ^ sw;
        int bo1 = (key * 128 + 64 + g * 16) ^ sw;
        bf16x8 bk0 = *reinterpret_cast<const bf16x8*>(lds + bo0);
        bf16x8 bk1 = *reinterpret_cast<const bf16x8*>(lds + bo1);
        S[jt] = __builtin_amdgcn_mfma_f32_16x16x32_bf16(aq0, bk0, S[jt], 0, 0, 0);
        S[jt] = __builtin_amdgcn_mfma_f32_16x16x32_bf16(aq1, bk1, S[jt], 0, 0, 0);
    }

    // ---- softmax over 256 keys ----
    float rmax[4] = {-3e38f, -3e38f, -3e38f, -3e38f};
    #pragma unroll
    for (int jt = 0; jt < 16; ++jt)
        #pragma unroll
        for (int r = 0; r < 4; ++r) {
            float s = S[jt][r] * 0.125f;
            S[jt][r] = s;
            rmax[r] = fmaxf(rmax[r], s);
        }
    #pragma unroll
    for (int r = 0; r < 4; ++r) {
        rmax[r] = fmaxf(rmax[r], __shfl_xor(rmax[r], 1));
        rmax[r] = fmaxf(rmax[r], __shfl_xor(rmax[r], 2));
        rmax[r] = fmaxf(rmax[r], __shfl_xor(rmax[r], 4));
        rmax[r] = fmaxf(rmax[r], __shfl_xor(rmax[r], 8));
    }
    float rsum[4] = {0.f, 0.f, 0.f, 0.f};
    #pragma unroll
    for (int jt = 0; jt < 16; ++jt)
        #pragma unroll
        for (int r = 0; r < 4; ++r) {
            float e = __expf(S[jt][r] - rmax[r]);
            S[jt][r] = e;
            rsum[r] += e;
        }
    #pragma unroll
    for (int r = 0; r < 4; ++r) {
        rsum[r] += __shfl_xor(rsum[r], 1);
        rsum[r] += __shfl_xor(rsum[r], 2);
        rsum[r] += __shfl_xor(rsum[r], 4);
        rsum[r] += __shfl_xor(rsum[r], 8);
    }

    __syncthreads();   // all waves done reading K; overlay P
    char* Pw = lds + wid * 8192;
    #pragma unroll
    for (int jt = 0; jt < 16; ++jt)
        #pragma unroll
        for (int r = 0; r < 4; ++r) {
            int row = g * 4 + r;
            int bo = row * 512 + (jt * 16 + c) * 2;
            bo ^= (row & 7) << 4;
            *reinterpret_cast<__bf16*>(Pw + bo) = (__bf16)S[jt][r];
        }
    __syncthreads();

    // ---- O = P V, both from LDS ----
    f32x4 O[4];
    #pragma unroll
    for (int dt = 0; dt < 4; ++dt) O[dt] = (f32x4){0.f, 0.f, 0.f, 0.f};

    #pragma unroll
    for (int mc = 0; mc < 8; ++mc) {
        int bo = c * 512 + (mc * 32 + g * 8) * 2;
        bo ^= (c & 7) << 4;
        bf16x8 ap = *reinterpret_cast<const bf16x8*>(Pw + bo);
        #pragma unroll
        for (int dt = 0; dt < 4; ++dt) {
            int vrow = dt * 16 + c;
            int vbo = 32768 + ((vrow * 512 + mc * 64 + g * 16) ^ ((vrow & 7) << 4));
            bf16x8 bv = *reinterpret_cast<const bf16x8*>(lds + vbo);
            O[dt] = __builtin_amdgcn_mfma_f32_16x16x32_bf16(ap, bv, O[dt], 0, 0, 0);
        }
    }

    #pragma unroll
    for (int dt = 0; dt < 4; ++dt)
        #pragma unroll
        for (int r = 0; r < 4; ++r) {
            int n = b * 256 + qb * 16 + g * 4 + r;
            int col = h * 64 + dt * 16 + c;
            od[(size_t)n * 256 + col] = (__bf16)(O[dt][r] / rsum[r]);
        }
}

// ---------------------------------------------------------------------------
// fusion + LayerNorm, f32 output. one wave per row; lane owns 4 consecutive cols.
__global__ __launch_bounds__(256) void fuse_ln(const float* __restrict__ x,
                                               const __bf16* __restrict__ aggb,
                                               const __bf16* __restrict__ skipb,
                                               const __bf16* __restrict__ od2b,
                                               const float* __restrict__ wl_p,
                                               const float* __restrict__ wg_p,
                                               const float* __restrict__ gam,
                                               const float* __restrict__ bet,
                                               float* __restrict__ out, int tot) {
    int w = (blockIdx.x * 256 + threadIdx.x) >> 6;
    int lane = threadIdx.x & 63;
    if (w >= tot) return;
    const float wl = wl_p[0], wg = wg_p[0];
    size_t base = (size_t)w * 256;
    float4 xv = reinterpret_cast<const float4*>(x + base)[lane];
    ushort4 ag = reinterpret_cast<const ushort4*>(aggb + base)[lane];
    ushort4 sk = reinterpret_cast<const ushort4*>(skipb + base)[lane];
    ushort4 o2 = reinterpret_cast<const ushort4*>(od2b + base)[lane];
    float v[4];
    v[0] = wl * (us2f(ag.x) + us2f(sk.x)) + wg * (us2f(o2.x) + xv.x) + xv.x;
    v[1] = wl * (us2f(ag.y) + us2f(sk.y)) + wg * (us2f(o2.y) + xv.y) + xv.y;
    v[2] = wl * (us2f(ag.z) + us2f(sk.z)) + wg * (us2f(o2.z) + xv.z) + xv.z;
    v[3] = wl * (us2f(ag.w) + us2f(sk.w)) + wg * (us2f(o2.w) + xv.w) + xv.w;

    float s = v[0] + v[1] + v[2] + v[3];
    #pragma unroll
    for (int off = 32; off; off >>= 1) s += __shfl_xor(s, off);
    float mu = s * (1.0f / 256.0f);
    float e[4], ss = 0.f;
    #pragma unroll
    for (int j = 0; j < 4; ++j) { e[j] = v[j] - mu; ss += e[j] * e[j]; }
    #pragma unroll
    for (int off = 32; off; off >>= 1) ss += __shfl_xor(ss, off);
    float rstd = rsqrtf(ss * (1.0f / 256.0f) + 1e-5f);
    float4 go;
    int c0 = lane * 4;
    go.x = e[0] * rstd * gam[c0 + 0] + bet[c0 + 0];
    go.y = e[1] * rstd * gam[c0 + 1] + bet[c0 + 1];
    go.z = e[2] * rstd * gam[c0 + 2] + bet[c0 + 2];
    go.w = e[3] * rstd * gam[c0 + 3] + bet[c0 + 3];
    reinterpret_cast<float4*>(out + base)[lane] = go;
}

// ---------------------------------------------------------------------------
extern "C" void kernel_launch(void* const* d_in, const int* in_sizes, int n_in,
                              void* d_out, int out_size, void* d_ws, size_t ws_size,
                              hipStream_t stream) {
    const float* x    = (const float*)d_in[0];
    const int*   ei   = (const int*)d_in[1];
    const float* lq_w = (const float*)d_in[3];  const float* lq_b = (const float*)d_in[4];
    const float* lk_w = (const float*)d_in[5];  const float* lk_b = (const float*)d_in[6];
    const float* lv_w = (const float*)d_in[7];  const float* lv_b = (const float*)d_in[8];
    const float* ls_w = (const float*)d_in[9];  const float* ls_b = (const float*)d_in[10];
    const float* gq_w = (const float*)d_in[11]; const float* gq_b = (const float*)d_in[12];
    const float* gk_w = (const float*)d_in[13]; const float* gk_b = (const float*)d_in[14];
    const float* gv_w = (const float*)d_in[15]; const float* gv_b = (const float*)d_in[16];
    const float* go_w = (const float*)d_in[17]; const float* go_b = (const float*)d_in[18];
    const float* wl   = (const float*)d_in[19]; const float* wg   = (const float*)d_in[20];
    const float* ln_g = (const float*)d_in[21]; const float* ln_b = (const float*)d_in[22];

    const int TOT = in_sizes[0] / D_DIM;
    const int E = in_sizes[1] / 2;
    const int B = TOT / NPG;
    const size_t S = (size_t)TOT * D_DIM;

    // workspace layout: 11 x S bf16 + wt + bucket/deg
    __bf16* xpk   = (__bf16*)d_ws;      // S (fragment-packed x)
    __bf16* qg    = xpk + S;
    __bf16* kg    = qg + S;
    __bf16* aggb  = kg + S;             // S (local-attn output, bf16)
    __bf16* ql    = aggb + S;
    __bf16* kl    = ql + S;
    __bf16* vl    = kl + S;
    __bf16* skipb = vl + S;
    __bf16* od2b  = skipb + S;
    __bf16* Vt    = od2b + S;           // S (written directly by proj_csr)
    __bf16* od    = Vt + S;             // S
    __bf16* wt    = od + S;             // 8 x 65536 (fragment-packed)
    int* bucket = (int*)(wt + 8 * 65536);   // TOT*BCAP
    int* deg    = bucket + (size_t)TOT * BCAP;

    // ---- 1. merged prep (pack x, pack W, zero deg) ----
    const int nb1 = TOT / 16;
    const int nbz = (TOT + 255) / 256;
    prep_misc<<<nb1 + 128 + nbz, 256, 0, stream>>>(x, xpk,
        gq_w, gk_w, gv_w, go_w, lq_w, lk_w, lv_w, ls_w, wt, deg, nb1, TOT);

    // ---- 2. fused 7-projection GEMM + edge-bucket build ----
    const int nb_gemm = (TOT / 256) * 28;
    const int nb_edge = (E + 511) / 512;
    proj_csr<<<nb_gemm + nb_edge, 512, 0, stream>>>(xpk, wt,
        gq_b, gk_b, gv_b, lq_b, lk_b, lv_b, ls_b,
        qg, kg, Vt, ql, kl, vl, skipb,
        ei, bucket, deg, E, nb_gemm, TOT);

    // ---- 3. global attention ----
    global_attn_mfma<<<B * HEADS * 4, 256, 0, stream>>>(qg, kg, Vt, od);

    // ---- 4. local attention ----
    local_attn_bf16<<<TOT / 4, 256, 0, stream>>>(ql, kl, vl, bucket, deg, aggb, TOT);

    // ---- 5. go GEMM ----
    __bf16* wt_go = wt + 3 * 65536;
    gemm_go<<<dim3(TOT / 64, 4), 256, 0, stream>>>(od, wt_go, go_b, od2b, TOT);

    // ---- 6. fuse + layernorm -> f32 out ----
    fuse_ln<<<(TOT + 3) / 4, 256, 0, stream>>>(x, aggb, skipb, od2b, wl, wg, ln_g, ln_b,
                                               (float*)d_out, TOT);
}

// Round 17
// 124.264 us; speedup vs baseline: 1.1828x; 1.1828x over previous
//
#include <hip/hip_runtime.h>
#include <hip/hip_bf16.h>

#define D_DIM 256
#define NPG   256
#define HEADS 4
#define HD    64
#define BCAP  64   // per-node edge bucket capacity (deg ~ Poisson(16))

typedef __bf16 bf16x8 __attribute__((ext_vector_type(8)));
typedef __bf16 bf16x4 __attribute__((ext_vector_type(4)));
typedef float  f32x4  __attribute__((ext_vector_type(4)));

__device__ inline float us2f(unsigned short u) {
    union { unsigned int i; float f; } cv; cv.i = ((unsigned int)u) << 16; return cv.f;
}

// async global->LDS, 16B per lane (dest = wave-uniform base + lane*16)
#define GLOAD_LDS16(g, l) __builtin_amdgcn_global_load_lds(                    \
    (const __attribute__((address_space(1))) void*)(g),                        \
    (__attribute__((address_space(3))) void*)(l), 16, 0, 0)

// ---------------------------------------------------------------------------
// merged prep: [0,nb1) convert_pack_x | [nb1,nb1+128) transpose_pack_w8 |
//              [nb1+128, ...) zero deg
__global__ __launch_bounds__(256) void prep_misc(const float* __restrict__ x,
                                                 __bf16* __restrict__ xpk,
        const float* w0, const float* w1, const float* w2, const float* w3,
        const float* w4, const float* w5, const float* w6, const float* w7,
        __bf16* __restrict__ wt, int* __restrict__ zeros, int nb1, int tot) {
    __shared__ __bf16 tile[256][16];
    int bid = blockIdx.x;
    const int t = threadIdx.x;
    if (bid < nb1) {
        const int rt = bid;
        const int ks = t >> 5;
        #pragma unroll
        for (int h2 = 0; h2 < 2; ++h2) {
            int lane = (t & 31) * 2 + h2;
            int row = rt * 16 + (lane & 15);
            int col = ks * 32 + (lane >> 4) * 8;
            const float4* src = reinterpret_cast<const float4*>(x + (size_t)row * 256 + col);
            float4 f0 = src[0], f1 = src[1];
            __bf16* o = xpk + ((size_t)(rt * 8 + ks) * 64 + lane) * 8;
            o[0] = (__bf16)f0.x; o[1] = (__bf16)f0.y; o[2] = (__bf16)f0.z; o[3] = (__bf16)f0.w;
            o[4] = (__bf16)f1.x; o[5] = (__bf16)f1.y; o[6] = (__bf16)f1.z; o[7] = (__bf16)f1.w;
        }
        return;
    }
    bid -= nb1;
    if (bid < 128) {
        const float* Ws[8] = {w0, w1, w2, w3, w4, w5, w6, w7};
        const int jt2 = bid & 15, wsel = bid >> 4;
        const float* W = Ws[wsel];
        const float4* wr = reinterpret_cast<const float4*>(W + (size_t)t * 256 + jt2 * 16);
        #pragma unroll
        for (int u = 0; u < 4; ++u) {
            float4 f = wr[u];
            tile[t][u * 4 + 0] = (__bf16)f.x; tile[t][u * 4 + 1] = (__bf16)f.y;
            tile[t][u * 4 + 2] = (__bf16)f.z; tile[t][u * 4 + 3] = (__bf16)f.w;
        }
        __syncthreads();
        __bf16* out = wt + ((size_t)wsel * 16 + jt2) * 4096;
        #pragma unroll
        for (int u = 0; u < 16; ++u) {
            int e = t * 16 + u;
            int ks = e >> 9, lane = (e >> 3) & 63, i = e & 7;
            int g = lane >> 4, c = lane & 15;
            int k = ks * 32 + g * 8 + i;
            out[e] = tile[k][c];
        }
        return;
    }
    bid -= 128;
    int i = bid * 256 + t;
    if (i < tot) zeros[i] = 0;
}

// ---------------------------------------------------------------------------
// Fused: 7-projection GEMM (blocks [0,nb_gemm)) + edge-bucket build (rest).
// XCD-swizzled x so each XCD's A working set is 1MB (L2-resident).
// A-loads: 4+4 double-buffer issued entirely AFTER the barrier (no
// cross-barrier liveness -> no spills). No launch_bounds VGPR cap.
__global__ __launch_bounds__(512) void proj_csr(const __bf16* __restrict__ xpk,
                                                const __bf16* __restrict__ wt,
        const float* b_gq, const float* b_gk, const float* b_gv,
        const float* b_lq, const float* b_lk, const float* b_lv, const float* b_ls,
        __bf16* o_gq, __bf16* o_gk, __bf16* Vt,
        __bf16* o_lq, __bf16* o_lk, __bf16* o_lv, __bf16* o_ls,
        const int* __restrict__ ei_raw, int* __restrict__ bucket,
        int* __restrict__ deg, int E, int nb_gemm, int M) {
    __shared__ __align__(16) __bf16 wlds[16384];   // one packed W quarter (32KB)
    int bid = blockIdx.x;
    if (bid >= nb_gemm) {
        // ---- edge part: dtype detect + bucket scatter ----
        int v = ei_raw[2 * (threadIdx.x & 63) + 1];
        unsigned long long nz = __ballot(v != 0);
        bool is64 = (nz == 0ULL);
        int e = (bid - nb_gemm) * 512 + threadIdx.x;
        if (e >= E) return;
        int s, d;
        if (is64) { s = ei_raw[2 * e]; d = ei_raw[2 * (E + e)]; }
        else      { s = ei_raw[e];     d = ei_raw[E + e]; }
        int p = atomicAdd(&deg[d], 1);
        if (p < BCAP) bucket[d * BCAP + p] = s;
        return;
    }
    const int gx = M >> 8;            // row-blocks (256 rows); divisible by 8
    const int cpx = gx >> 3;
    const int xcd = bid & 7;
    const int local = bid >> 3;
    const int x = xcd * cpx + (local % cpx);
    const int y = local / cpx;
    const int j = y >> 2;
    const int q = y & 3;
    const int wsel = (j < 3) ? j : j + 1;
    const float* bias = (j == 0) ? b_gq : (j == 1) ? b_gk : (j == 2) ? b_gv :
                        (j == 3) ? b_lq : (j == 4) ? b_lk : (j == 5) ? b_lv : b_ls;
    __bf16* C = (j == 0) ? o_gq : (j == 1) ? o_gk : (j == 2) ? nullptr :
                (j == 3) ? o_lq : (j == 4) ? o_lk : (j == 5) ? o_lv : o_ls;

    // async stage of the 32KB packed-W quarter (linear LDS, 16B/lane)
    {
        const __bf16* gs = wt + (size_t)wsel * 65536 + (size_t)q * 16384;
        #pragma unroll
        for (int it = 0; it < 4; ++it) {
            int ch = it * 512 + threadIdx.x;
            GLOAD_LDS16(gs + ch * 8, wlds + ch * 8);
        }
    }

    const int wid = threadIdx.x >> 6, lane = threadIdx.x & 63;
    const int g = lane >> 4, c = lane & 15;
    const int rt0 = x * 16 + wid * 2;
    const char* wl = reinterpret_cast<const char*>(wlds) + lane * 16;

    __syncthreads();   // drains gload_lds (vmcnt) + orders LDS

    #pragma unroll
    for (int h = 0; h < 2; ++h) {
        const __bf16* ap = xpk + ((size_t)(rt0 + h) * 8) * 512 + lane * 8;
        bf16x8 afA[4];
        #pragma unroll
        for (int i = 0; i < 4; ++i)
            afA[i] = *reinterpret_cast<const bf16x8*>(ap + i * 512);

        f32x4 acc[4];
        #pragma unroll
        for (int jt = 0; jt < 4; ++jt) acc[jt] = (f32x4){0.f, 0.f, 0.f, 0.f};

        bf16x8 afB[4];
        #pragma unroll
        for (int ks = 0; ks < 4; ++ks) {
            afB[ks] = *reinterpret_cast<const bf16x8*>(ap + (ks + 4) * 512);
            #pragma unroll
            for (int jt = 0; jt < 4; ++jt) {
                bf16x8 bf_ = *reinterpret_cast<const bf16x8*>(wl + (jt * 8 + ks) * 1024);
                acc[jt] = __builtin_amdgcn_mfma_f32_16x16x32_bf16(bf_, afA[ks], acc[jt], 0, 0, 0);
            }
        }
        #pragma unroll
        for (int ks = 4; ks < 8; ++ks) {
            #pragma unroll
            for (int jt = 0; jt < 4; ++jt) {
                bf16x8 bf_ = *reinterpret_cast<const bf16x8*>(wl + (jt * 8 + ks) * 1024);
                acc[jt] = __builtin_amdgcn_mfma_f32_16x16x32_bf16(bf_, afB[ks - 4], acc[jt], 0, 0, 0);
            }
        }

        if (j == 2) {
            int m = (rt0 + h) * 16 + c;
            int b = m >> 8, mm = m & 255;
            #pragma unroll
            for (int jt = 0; jt < 4; ++jt) {
                int col0 = q * 64 + jt * 16 + g * 4;
                float4 bv = *reinterpret_cast<const float4*>(bias + col0);
                Vt[(size_t)(b * 256 + col0 + 0) * 256 + mm] = (__bf16)(acc[jt][0] + bv.x);
                Vt[(size_t)(b * 256 + col0 + 1) * 256 + mm] = (__bf16)(acc[jt][1] + bv.y);
                Vt[(size_t)(b * 256 + col0 + 2) * 256 + mm] = (__bf16)(acc[jt][2] + bv.z);
                Vt[(size_t)(b * 256 + col0 + 3) * 256 + mm] = (__bf16)(acc[jt][3] + bv.w);
            }
        } else {
            int row = (rt0 + h) * 16 + c;
            #pragma unroll
            for (int jt = 0; jt < 4; ++jt) {
                int col0 = q * 64 + jt * 16 + g * 4;
                float4 bv = *reinterpret_cast<const float4*>(bias + col0);
                bf16x4 st;
                st[0] = (__bf16)(acc[jt][0] + bv.x);
                st[1] = (__bf16)(acc[jt][1] + bv.y);
                st[2] = (__bf16)(acc[jt][2] + bv.z);
                st[3] = (__bf16)(acc[jt][3] + bv.w);
                *reinterpret_cast<bf16x4*>(&C[(size_t)row * 256 + col0]) = st;
            }
        }
    }
}

// ---------------------------------------------------------------------------
// MFMA global attention: K and V both staged in LDS (swizzled); P overlays K.
__global__ __launch_bounds__(256) void global_attn_mfma(const __bf16* __restrict__ Qb,
                                                        const __bf16* __restrict__ Kb,
                                                        const __bf16* __restrict__ Vt,
                                                        __bf16* __restrict__ od) {
    __shared__ __align__(16) char lds[65536];   // [0,32K): K then P; [32K,64K): V
    const int tid = threadIdx.x;
    const int wid = tid >> 6, lane = tid & 63;
    const int bh = blockIdx.x >> 2, qq = blockIdx.x & 3;
    const int b = bh >> 2, h = bh & 3;
    const int qb = qq * 4 + wid;
    const int g = lane >> 4, c = lane & 15;

    // ---- stage K slice (32KB) ----
    {
        const __bf16* kgp = Kb + ((size_t)b * 256) * 256 + h * 64;
        int krow = tid >> 3, ch = tid & 7;
        #pragma unroll
        for (int p = 0; p < 8; ++p) {
            int kk = p * 32 + krow;
            bf16x8 val = *reinterpret_cast<const bf16x8*>(kgp + (size_t)kk * 256 + ch * 8);
            int bo = (kk * 128 + ch * 16) ^ ((kk & 7) << 4);
            *reinterpret_cast<bf16x8*>(lds + bo) = val;
        }
    }
    // ---- stage V slice (32KB), row-major [64][256], swizzled ----
    {
        const bf16x8* vgp = reinterpret_cast<const bf16x8*>(Vt + (size_t)bh * 16384);
        #pragma unroll
        for (int p = 0; p < 8; ++p) {
            int off = p * 256 + tid;
            bf16x8 val = vgp[off];
            int row = off >> 5;
            int colb = (off & 31) * 16;
            int bo = 32768 + ((row * 512 + colb) ^ ((row & 7) << 4));
            *reinterpret_cast<bf16x8*>(lds + bo) = val;
        }
    }
    const __bf16* qptr = Qb + ((size_t)(b * 256 + qb * 16 + c)) * 256 + h * 64 + g * 8;
    bf16x8 aq0 = *reinterpret_cast<const bf16x8*>(qptr);
    bf16x8 aq1 = *reinterpret_cast<const bf16x8*>(qptr + 32);
    __syncthreads();

    // ---- QK^T from LDS ----
    f32x4 S[16];
    #pragma unroll
    for (int jt = 0; jt < 16; ++jt) S[jt] = (f32x4){0.f, 0.f, 0.f, 0.f};
    #pragma unroll
    for (int jt = 0; jt < 16; ++jt) {
        int key = jt * 16 + c;
        int sw = (key & 7) << 4;
        int bo0 = (key * 128 + g * 16) ^ sw;
        int bo1 = (key * 128 + 64 + g * 16) ^ sw;
        bf16x8 bk0 = *reinterpret_cast<const bf16x8*>(lds + bo0);
        bf16x8 bk1 = *reinterpret_cast<const bf16x8*>(lds + bo1);
        S[jt] = __builtin_amdgcn_mfma_f32_16x16x32_bf16(aq0, bk0, S[jt], 0, 0, 0);
        S[jt] = __builtin_amdgcn_mfma_f32_16x16x32_bf16(aq1, bk1, S[jt], 0, 0, 0);
    }

    // ---- softmax over 256 keys ----
    float rmax[4] = {-3e38f, -3e38f, -3e38f, -3e38f};
    #pragma unroll
    for (int jt = 0; jt < 16; ++jt)
        #pragma unroll
        for (int r = 0; r < 4; ++r) {
            float s = S[jt][r] * 0.125f;
            S[jt][r] = s;
            rmax[r] = fmaxf(rmax[r], s);
        }
    #pragma unroll
    for (int r = 0; r < 4; ++r) {
        rmax[r] = fmaxf(rmax[r], __shfl_xor(rmax[r], 1));
        rmax[r] = fmaxf(rmax[r], __shfl_xor(rmax[r], 2));
        rmax[r] = fmaxf(rmax[r], __shfl_xor(rmax[r], 4));
        rmax[r] = fmaxf(rmax[r], __shfl_xor(rmax[r], 8));
    }
    float rsum[4] = {0.f, 0.f, 0.f, 0.f};
    #pragma unroll
    for (int jt = 0; jt < 16; ++jt)
        #pragma unroll
        for (int r = 0; r < 4; ++r) {
            float e = __expf(S[jt][r] - rmax[r]);
            S[jt][r] = e;
            rsum[r] += e;
        }
    #pragma unroll
    for (int r = 0; r < 4; ++r) {
        rsum[r] += __shfl_xor(rsum[r], 1);
        rsum[r] += __shfl_xor(rsum[r], 2);
        rsum[r] += __shfl_xor(rsum[r], 4);
        rsum[r] += __shfl_xor(rsum[r], 8);
    }

    __syncthreads();   // all waves done reading K; overlay P
    char* Pw = lds + wid * 8192;
    #pragma unroll
    for (int jt = 0; jt < 16; ++jt)
        #pragma unroll
        for (int r = 0; r < 4; ++r) {
            int row = g * 4 + r;
            int bo = row * 512 + (jt * 16 + c) * 2;
            bo ^= (row & 7) << 4;
            *reinterpret_cast<__bf16*>(Pw + bo) = (__bf16)S[jt][r];
        }
    __syncthreads();

    // ---- O = P V, both from LDS ----
    f32x4 O[4];
    #pragma unroll
    for (int dt = 0; dt < 4; ++dt) O[dt] = (f32x4){0.f, 0.f, 0.f, 0.f};

    #pragma unroll
    for (int mc = 0; mc < 8; ++mc) {
        int bo = c * 512 + (mc * 32 + g * 8) * 2;
        bo ^= (c & 7) << 4;
        bf16x8 ap = *reinterpret_cast<const bf16x8*>(Pw + bo);
        #pragma unroll
        for (int dt = 0; dt < 4; ++dt) {
            int vrow = dt * 16 + c;
            int vbo = 32768 + ((vrow * 512 + mc * 64 + g * 16) ^ ((vrow & 7) << 4));
            bf16x8 bv = *reinterpret_cast<const bf16x8*>(lds + vbo);
            O[dt] = __builtin_amdgcn_mfma_f32_16x16x32_bf16(ap, bv, O[dt], 0, 0, 0);
        }
    }

    #pragma unroll
    for (int dt = 0; dt < 4; ++dt)
        #pragma unroll
        for (int r = 0; r < 4; ++r) {
            int n = b * 256 + qb * 16 + g * 4 + r;
            int col = h * 64 + dt * 16 + c;
            od[(size_t)n * 256 + col] = (__bf16)(O[dt][r] / rsum[r]);
        }
}

// ---------------------------------------------------------------------------
// Merged: local attention (blocks [0,nlb)) + go GEMM (blocks [nlb, nlb+nb_go)).
// Both paths 256 threads; go path uses the 32KB LDS, local path ignores it.
__global__ __launch_bounds__(256) void lattn_go(
        const __bf16* __restrict__ ql, const __bf16* __restrict__ kl,
        const __bf16* __restrict__ vl,
        const int* __restrict__ bucket, const int* __restrict__ deg,
        __bf16* __restrict__ aggb,
        const __bf16* __restrict__ od, const __bf16* __restrict__ Wp,
        const float* __restrict__ go_b, __bf16* __restrict__ od2b,
        int nlb, int M, int tot) {
    __shared__ __align__(16) __bf16 wlds[16384];
    int bid = blockIdx.x;
    const int wid = threadIdx.x >> 6, lane = threadIdx.x & 63;
    const int g = lane >> 4, c = lane & 15;

    if (bid >= nlb) {
        // ---- go GEMM path ----
        int gb = bid - nlb;
        const int gxg = M >> 6;
        const int bx = gb % gxg, by = gb / gxg;
        {
            const __bf16* gs = Wp + (size_t)by * 16384;
            #pragma unroll
            for (int it = 0; it < 8; ++it) {
                int chunk = it * 256 + threadIdx.x;
                GLOAD_LDS16(gs + chunk * 8, wlds + chunk * 8);
            }
        }
        const int row0 = bx * 64 + wid * 16;
        const __bf16* arow = od + (size_t)(row0 + c) * 256 + g * 8;
        bf16x8 af = *reinterpret_cast<const bf16x8*>(arow);

        f32x4 acc[4];
        #pragma unroll
        for (int jt = 0; jt < 4; ++jt) acc[jt] = (f32x4){0.f, 0.f, 0.f, 0.f};

        const char* wl = reinterpret_cast<const char*>(wlds) + lane * 16;
        __syncthreads();
        #pragma unroll
        for (int ks = 0; ks < 8; ++ks) {
            bf16x8 nf;
            if (ks < 7) nf = *reinterpret_cast<const bf16x8*>(arow + (ks + 1) * 32);
            #pragma unroll
            for (int jt = 0; jt < 4; ++jt) {
                bf16x8 bf_ = *reinterpret_cast<const bf16x8*>(wl + (jt * 8 + ks) * 1024);
                acc[jt] = __builtin_amdgcn_mfma_f32_16x16x32_bf16(bf_, af, acc[jt], 0, 0, 0);
            }
            af = nf;
        }
        int row = row0 + c;
        #pragma unroll
        for (int jt = 0; jt < 4; ++jt) {
            int col0 = by * 64 + jt * 16 + g * 4;
            float4 bv = *reinterpret_cast<const float4*>(go_b + col0);
            bf16x4 st;
            st[0] = (__bf16)(acc[jt][0] + bv.x);
            st[1] = (__bf16)(acc[jt][1] + bv.y);
            st[2] = (__bf16)(acc[jt][2] + bv.z);
            st[3] = (__bf16)(acc[jt][3] + bv.w);
            *reinterpret_cast<bf16x4*>(&od2b[(size_t)row * 256 + col0]) = st;
        }
        return;
    }

    // ---- local attention path (XCD-contiguous swizzle within [0,nlb)) ----
    int lb = (bid & 7) * (nlb >> 3) + (bid >> 3);
    int w = (lb * 256 + (int)threadIdx.x) >> 6;
    if (w >= tot) return;
    const int t = w;
    const int cc = c;   // alias

    float qf[16];
    {
        const ushort4* qr = reinterpret_cast<const ushort4*>(ql + (size_t)t * 256);
        #pragma unroll
        for (int u = 0; u < 4; ++u) {
            ushort4 qv = qr[cc * 4 + u];
            qf[u * 4 + 0] = us2f(qv.x); qf[u * 4 + 1] = us2f(qv.y);
            qf[u * 4 + 2] = us2f(qv.z); qf[u * 4 + 3] = us2f(qv.w);
        }
    }

    int dg = deg[t];
    if (dg > BCAP) dg = BCAP;
    const int* bkt = bucket + (size_t)t * BCAP;
    float M_ = -3.0e38f, den = 0.f;
    float a0 = 0.f, a1 = 0.f, a2 = 0.f, a3 = 0.f;

    for (int i0 = 0; i0 < dg; i0 += 4) {
        bool valid = (i0 + g) < dg;
        int s = valid ? bkt[i0 + g] : 0;

        float p = 0.f;
        const ushort4* kr = reinterpret_cast<const ushort4*>(kl + (size_t)s * 256);
        #pragma unroll
        for (int u = 0; u < 4; ++u) {
            ushort4 kv = kr[cc * 4 + u];
            p += qf[u * 4 + 0] * us2f(kv.x) + qf[u * 4 + 1] * us2f(kv.y)
               + qf[u * 4 + 2] * us2f(kv.z) + qf[u * 4 + 3] * us2f(kv.w);
        }
        p += __shfl_xor(p, 1); p += __shfl_xor(p, 2);
        p += __shfl_xor(p, 4); p += __shfl_xor(p, 8);

        float lg[4]; int sj[4];
        #pragma unroll
        for (int jj = 0; jj < 4; ++jj) {
            float pj = __shfl(p, jj * 16);
            int   ssj = __shfl(s, jj * 16);
            bool vj = (i0 + jj) < dg;
            lg[jj] = vj ? pj * 0.0625f : -3.0e38f;
            sj[jj] = vj ? ssj : 0;
        }

        float nM = fmaxf(fmaxf(fmaxf(lg[0], lg[1]), fmaxf(lg[2], lg[3])), M_);
        float sc = __expf(M_ - nM);
        float ex[4];
        #pragma unroll
        for (int jj = 0; jj < 4; ++jj) ex[jj] = __expf(lg[jj] - nM);

        float s0 = 0.f, s1 = 0.f, s2 = 0.f, s3 = 0.f;
        #pragma unroll
        for (int jj = 0; jj < 4; ++jj) {
            ushort4 vv = reinterpret_cast<const ushort4*>(vl + (size_t)sj[jj] * 256)[lane];
            s0 += ex[jj] * us2f(vv.x); s1 += ex[jj] * us2f(vv.y);
            s2 += ex[jj] * us2f(vv.z); s3 += ex[jj] * us2f(vv.w);
        }
        a0 = a0 * sc + s0; a1 = a1 * sc + s1;
        a2 = a2 * sc + s2; a3 = a3 * sc + s3;
        den = den * sc + ex[0] + ex[1] + ex[2] + ex[3];
        M_ = nM;
    }
    float inv = (dg > 0) ? 1.0f / den : 0.0f;
    bf16x4 o;
    o[0] = (__bf16)(a0 * inv); o[1] = (__bf16)(a1 * inv);
    o[2] = (__bf16)(a2 * inv); o[3] = (__bf16)(a3 * inv);
    reinterpret_cast<bf16x4*>(aggb + (size_t)t * 256)[lane] = o;
}

// ---------------------------------------------------------------------------
// fusion + LayerNorm, f32 output. one wave per row; lane owns 4 consecutive cols.
__global__ __launch_bounds__(256) void fuse_ln(const float* __restrict__ x,
                                               const __bf16* __restrict__ aggb,
                                               const __bf16* __restrict__ skipb,
                                               const __bf16* __restrict__ od2b,
                                               const float* __restrict__ wl_p,
                                               const float* __restrict__ wg_p,
                                               const float* __restrict__ gam,
                                               const float* __restrict__ bet,
                                               float* __restrict__ out, int tot) {
    int w = (blockIdx.x * 256 + threadIdx.x) >> 6;
    int lane = threadIdx.x & 63;
    if (w >= tot) return;
    const float wl = wl_p[0], wg = wg_p[0];
    size_t base = (size_t)w * 256;
    float4 xv = reinterpret_cast<const float4*>(x + base)[lane];
    ushort4 ag = reinterpret_cast<const ushort4*>(aggb + base)[lane];
    ushort4 sk = reinterpret_cast<const ushort4*>(skipb + base)[lane];
    ushort4 o2 = reinterpret_cast<const ushort4*>(od2b + base)[lane];
    float v[4];
    v[0] = wl * (us2f(ag.x) + us2f(sk.x)) + wg * (us2f(o2.x) + xv.x) + xv.x;
    v[1] = wl * (us2f(ag.y) + us2f(sk.y)) + wg * (us2f(o2.y) + xv.y) + xv.y;
    v[2] = wl * (us2f(ag.z) + us2f(sk.z)) + wg * (us2f(o2.z) + xv.z) + xv.z;
    v[3] = wl * (us2f(ag.w) + us2f(sk.w)) + wg * (us2f(o2.w) + xv.w) + xv.w;

    float s = v[0] + v[1] + v[2] + v[3];
    #pragma unroll
    for (int off = 32; off; off >>= 1) s += __shfl_xor(s, off);
    float mu = s * (1.0f / 256.0f);
    float e[4], ss = 0.f;
    #pragma unroll
    for (int j = 0; j < 4; ++j) { e[j] = v[j] - mu; ss += e[j] * e[j]; }
    #pragma unroll
    for (int off = 32; off; off >>= 1) ss += __shfl_xor(ss, off);
    float rstd = rsqrtf(ss * (1.0f / 256.0f) + 1e-5f);
    float4 go;
    int c0 = lane * 4;
    go.x = e[0] * rstd * gam[c0 + 0] + bet[c0 + 0];
    go.y = e[1] * rstd * gam[c0 + 1] + bet[c0 + 1];
    go.z = e[2] * rstd * gam[c0 + 2] + bet[c0 + 2];
    go.w = e[3] * rstd * gam[c0 + 3] + bet[c0 + 3];
    reinterpret_cast<float4*>(out + base)[lane] = go;
}

// ---------------------------------------------------------------------------
extern "C" void kernel_launch(void* const* d_in, const int* in_sizes, int n_in,
                              void* d_out, int out_size, void* d_ws, size_t ws_size,
                              hipStream_t stream) {
    const float* x    = (const float*)d_in[0];
    const int*   ei   = (const int*)d_in[1];
    const float* lq_w = (const float*)d_in[3];  const float* lq_b = (const float*)d_in[4];
    const float* lk_w = (const float*)d_in[5];  const float* lk_b = (const float*)d_in[6];
    const float* lv_w = (const float*)d_in[7];  const float* lv_b = (const float*)d_in[8];
    const float* ls_w = (const float*)d_in[9];  const float* ls_b = (const float*)d_in[10];
    const float* gq_w = (const float*)d_in[11]; const float* gq_b = (const float*)d_in[12];
    const float* gk_w = (const float*)d_in[13]; const float* gk_b = (const float*)d_in[14];
    const float* gv_w = (const float*)d_in[15]; const float* gv_b = (const float*)d_in[16];
    const float* go_w = (const float*)d_in[17]; const float* go_b = (const float*)d_in[18];
    const float* wl   = (const float*)d_in[19]; const float* wg   = (const float*)d_in[20];
    const float* ln_g = (const float*)d_in[21]; const float* ln_b = (const float*)d_in[22];

    const int TOT = in_sizes[0] / D_DIM;
    const int E = in_sizes[1] / 2;
    const int B = TOT / NPG;
    const size_t S = (size_t)TOT * D_DIM;

    // workspace layout: 11 x S bf16 + wt + bucket/deg
    __bf16* xpk   = (__bf16*)d_ws;      // S (fragment-packed x)
    __bf16* qg    = xpk + S;
    __bf16* kg    = qg + S;
    __bf16* aggb  = kg + S;             // S (local-attn output, bf16)
    __bf16* ql    = aggb + S;
    __bf16* kl    = ql + S;
    __bf16* vl    = kl + S;
    __bf16* skipb = vl + S;
    __bf16* od2b  = skipb + S;
    __bf16* Vt    = od2b + S;           // S (written directly by proj_csr)
    __bf16* od    = Vt + S;             // S
    __bf16* wt    = od + S;             // 8 x 65536 (fragment-packed)
    int* bucket = (int*)(wt + 8 * 65536);   // TOT*BCAP
    int* deg    = bucket + (size_t)TOT * BCAP;

    // ---- 1. merged prep (pack x, pack W, zero deg) ----
    const int nb1 = TOT / 16;
    const int nbz = (TOT + 255) / 256;
    prep_misc<<<nb1 + 128 + nbz, 256, 0, stream>>>(x, xpk,
        gq_w, gk_w, gv_w, go_w, lq_w, lk_w, lv_w, ls_w, wt, deg, nb1, TOT);

    // ---- 2. fused 7-projection GEMM + edge-bucket build ----
    const int nb_gemm = (TOT / 256) * 28;
    const int nb_edge = (E + 511) / 512;
    proj_csr<<<nb_gemm + nb_edge, 512, 0, stream>>>(xpk, wt,
        gq_b, gk_b, gv_b, lq_b, lk_b, lv_b, ls_b,
        qg, kg, Vt, ql, kl, vl, skipb,
        ei, bucket, deg, E, nb_gemm, TOT);

    // ---- 3. global attention ----
    global_attn_mfma<<<B * HEADS * 4, 256, 0, stream>>>(qg, kg, Vt, od);

    // ---- 4. merged local attention + go GEMM ----
    __bf16* wt_go = wt + 3 * 65536;
    const int nlb = TOT / 4;
    const int nb_go = (TOT / 64) * 4;
    lattn_go<<<nlb + nb_go, 256, 0, stream>>>(ql, kl, vl, bucket, deg, aggb,
                                              od, wt_go, go_b, od2b,
                                              nlb, TOT, TOT);

    // ---- 5. fuse + layernorm -> f32 out ----
    fuse_ln<<<(TOT + 3) / 4, 256, 0, stream>>>(x, aggb, skipb, od2b, wl, wg, ln_g, ln_b,
                                               (float*)d_out, TOT);
}

// Round 18
// 109.775 us; speedup vs baseline: 1.3390x; 1.1320x over previous
//
#include <hip/hip_runtime.h>
#include <hip/hip_bf16.h>

#define D_DIM 256
#define NPG   256
#define HEADS 4
#define HD    64
#define BCAP  64   // per-node edge bucket capacity (deg ~ Poisson(16))

typedef __bf16 bf16x8 __attribute__((ext_vector_type(8)));
typedef __bf16 bf16x4 __attribute__((ext_vector_type(4)));
typedef float  f32x4  __attribute__((ext_vector_type(4)));

__device__ inline float us2f(unsigned short u) {
    union { unsigned int i; float f; } cv; cv.i = ((unsigned int)u) << 16; return cv.f;
}

// async global->LDS, 16B per lane (dest = wave-uniform base + lane*16)
#define GLOAD_LDS16(g, l) __builtin_amdgcn_global_load_lds(                    \
    (const __attribute__((address_space(1))) void*)(g),                        \
    (__attribute__((address_space(3))) void*)(l), 16, 0, 0)

// ---------------------------------------------------------------------------
// merged prep: [0,nb1) convert_pack_x | [nb1,nb1+128) transpose_pack_w8 |
//              [nb1+128, ...) zero deg
__global__ __launch_bounds__(256) void prep_misc(const float* __restrict__ x,
                                                 __bf16* __restrict__ xpk,
        const float* w0, const float* w1, const float* w2, const float* w3,
        const float* w4, const float* w5, const float* w6, const float* w7,
        __bf16* __restrict__ wt, int* __restrict__ zeros, int nb1, int tot) {
    __shared__ __bf16 tile[256][16];
    int bid = blockIdx.x;
    const int t = threadIdx.x;
    if (bid < nb1) {
        const int rt = bid;
        const int ks = t >> 5;
        #pragma unroll
        for (int h2 = 0; h2 < 2; ++h2) {
            int lane = (t & 31) * 2 + h2;
            int row = rt * 16 + (lane & 15);
            int col = ks * 32 + (lane >> 4) * 8;
            const float4* src = reinterpret_cast<const float4*>(x + (size_t)row * 256 + col);
            float4 f0 = src[0], f1 = src[1];
            __bf16* o = xpk + ((size_t)(rt * 8 + ks) * 64 + lane) * 8;
            o[0] = (__bf16)f0.x; o[1] = (__bf16)f0.y; o[2] = (__bf16)f0.z; o[3] = (__bf16)f0.w;
            o[4] = (__bf16)f1.x; o[5] = (__bf16)f1.y; o[6] = (__bf16)f1.z; o[7] = (__bf16)f1.w;
        }
        return;
    }
    bid -= nb1;
    if (bid < 128) {
        const float* Ws[8] = {w0, w1, w2, w3, w4, w5, w6, w7};
        const int jt2 = bid & 15, wsel = bid >> 4;
        const float* W = Ws[wsel];
        const float4* wr = reinterpret_cast<const float4*>(W + (size_t)t * 256 + jt2 * 16);
        #pragma unroll
        for (int u = 0; u < 4; ++u) {
            float4 f = wr[u];
            tile[t][u * 4 + 0] = (__bf16)f.x; tile[t][u * 4 + 1] = (__bf16)f.y;
            tile[t][u * 4 + 2] = (__bf16)f.z; tile[t][u * 4 + 3] = (__bf16)f.w;
        }
        __syncthreads();
        __bf16* out = wt + ((size_t)wsel * 16 + jt2) * 4096;
        #pragma unroll
        for (int u = 0; u < 16; ++u) {
            int e = t * 16 + u;
            int ks = e >> 9, lane = (e >> 3) & 63, i = e & 7;
            int g = lane >> 4, c = lane & 15;
            int k = ks * 32 + g * 8 + i;
            out[e] = tile[k][c];
        }
        return;
    }
    bid -= 128;
    int i = bid * 256 + t;
    if (i < tot) zeros[i] = 0;
}

// ---------------------------------------------------------------------------
// Fused: 7-projection GEMM (blocks [0,nb_gemm)) + edge-bucket build (rest).
// XCD-swizzled x (L2-resident A). Round-13 A-load pattern (VGPR-lean).
// NEW: LDS-bounce store epilogue (j!=2): acc -> swizzled 32KB LDS tile ->
// coalesced bf16x8 row stores (4 instr/wave, 16 lines each vs 16x64).
__global__ __launch_bounds__(512) void proj_csr(const __bf16* __restrict__ xpk,
                                                const __bf16* __restrict__ wt,
        const float* b_gq, const float* b_gk, const float* b_gv,
        const float* b_lq, const float* b_lk, const float* b_lv, const float* b_ls,
        __bf16* o_gq, __bf16* o_gk, __bf16* Vt,
        __bf16* o_lq, __bf16* o_lk, __bf16* o_lv, __bf16* o_ls,
        const int* __restrict__ ei_raw, int* __restrict__ bucket,
        int* __restrict__ deg, int E, int nb_gemm, int M) {
    __shared__ __align__(16) __bf16 wlds[16384];   // W quarter; later C-tile bounce
    int bid = blockIdx.x;
    if (bid >= nb_gemm) {
        // ---- edge part: dtype detect + bucket scatter ----
        int v = ei_raw[2 * (threadIdx.x & 63) + 1];
        unsigned long long nz = __ballot(v != 0);
        bool is64 = (nz == 0ULL);
        int e = (bid - nb_gemm) * 512 + threadIdx.x;
        if (e >= E) return;
        int s, d;
        if (is64) { s = ei_raw[2 * e]; d = ei_raw[2 * (E + e)]; }
        else      { s = ei_raw[e];     d = ei_raw[E + e]; }
        int p = atomicAdd(&deg[d], 1);
        if (p < BCAP) bucket[d * BCAP + p] = s;
        return;
    }
    const int gx = M >> 8;            // row-blocks (256 rows); divisible by 8
    const int cpx = gx >> 3;
    const int xcd = bid & 7;
    const int local = bid >> 3;
    const int x = xcd * cpx + (local % cpx);
    const int y = local / cpx;
    const int j = y >> 2;
    const int q = y & 3;
    const int wsel = (j < 3) ? j : j + 1;
    const float* bias = (j == 0) ? b_gq : (j == 1) ? b_gk : (j == 2) ? b_gv :
                        (j == 3) ? b_lq : (j == 4) ? b_lk : (j == 5) ? b_lv : b_ls;
    __bf16* C = (j == 0) ? o_gq : (j == 1) ? o_gk : (j == 2) ? nullptr :
                (j == 3) ? o_lq : (j == 4) ? o_lk : (j == 5) ? o_lv : o_ls;

    // async stage of the 32KB packed-W quarter (linear LDS, 16B/lane)
    {
        const __bf16* gs = wt + (size_t)wsel * 65536 + (size_t)q * 16384;
        #pragma unroll
        for (int it = 0; it < 4; ++it) {
            int ch = it * 512 + threadIdx.x;
            GLOAD_LDS16(gs + ch * 8, wlds + ch * 8);
        }
    }

    const int wid = threadIdx.x >> 6, lane = threadIdx.x & 63;
    const int g = lane >> 4, c = lane & 15;
    const int rt0 = x * 16 + wid * 2;
    const char* wl = reinterpret_cast<const char*>(wlds) + lane * 16;

    __syncthreads();   // drains gload_lds + orders LDS

    f32x4 acc[2][4];
    #pragma unroll
    for (int h = 0; h < 2; ++h)
        #pragma unroll
        for (int jt = 0; jt < 4; ++jt) acc[h][jt] = (f32x4){0.f, 0.f, 0.f, 0.f};

    const __bf16* ap0 = xpk + ((size_t)rt0 * 8) * 512 + lane * 8;
    const __bf16* ap1 = ap0 + 8 * 512;
    #pragma unroll
    for (int ks = 0; ks < 8; ++ks) {
        bf16x8 af0 = *reinterpret_cast<const bf16x8*>(ap0 + ks * 512);
        bf16x8 af1 = *reinterpret_cast<const bf16x8*>(ap1 + ks * 512);
        #pragma unroll
        for (int jt = 0; jt < 4; ++jt) {
            bf16x8 bf_ = *reinterpret_cast<const bf16x8*>(wl + (jt * 8 + ks) * 1024);
            acc[0][jt] = __builtin_amdgcn_mfma_f32_16x16x32_bf16(bf_, af0, acc[0][jt], 0, 0, 0);
            acc[1][jt] = __builtin_amdgcn_mfma_f32_16x16x32_bf16(bf_, af1, acc[1][jt], 0, 0, 0);
        }
    }

    if (j == 2) {
        // gv: scatter transposed into Vt[(b*256 + col)*256 + m%256]
        #pragma unroll
        for (int h = 0; h < 2; ++h) {
            int m = (rt0 + h) * 16 + c;
            int b = m >> 8, mm = m & 255;
            #pragma unroll
            for (int jt = 0; jt < 4; ++jt) {
                int col0 = q * 64 + jt * 16 + g * 4;
                float4 bv = *reinterpret_cast<const float4*>(bias + col0);
                Vt[(size_t)(b * 256 + col0 + 0) * 256 + mm] = (__bf16)(acc[h][jt][0] + bv.x);
                Vt[(size_t)(b * 256 + col0 + 1) * 256 + mm] = (__bf16)(acc[h][jt][1] + bv.y);
                Vt[(size_t)(b * 256 + col0 + 2) * 256 + mm] = (__bf16)(acc[h][jt][2] + bv.z);
                Vt[(size_t)(b * 256 + col0 + 3) * 256 + mm] = (__bf16)(acc[h][jt][3] + bv.w);
            }
        }
    } else {
        // ---- LDS-bounce epilogue ----
        __syncthreads();   // all waves done reading W
        char* ob = reinterpret_cast<char*>(wlds);
        #pragma unroll
        for (int h = 0; h < 2; ++h) {
            int row_local = wid * 32 + h * 16 + c;
            int swz = (row_local & 7) << 4;
            #pragma unroll
            for (int jt = 0; jt < 4; ++jt) {
                int col2 = jt * 16 + g * 4;
                float4 bv = *reinterpret_cast<const float4*>(bias + q * 64 + col2);
                bf16x4 st;
                st[0] = (__bf16)(acc[h][jt][0] + bv.x);
                st[1] = (__bf16)(acc[h][jt][1] + bv.y);
                st[2] = (__bf16)(acc[h][jt][2] + bv.z);
                st[3] = (__bf16)(acc[h][jt][3] + bv.w);
                int bo = (row_local * 128 + col2 * 2) ^ swz;
                *reinterpret_cast<bf16x4*>(ob + bo) = st;
            }
        }
        __syncthreads();
        // coalesced read + store: instr i covers 8 rows x 128B chunks
        #pragma unroll
        for (int i = 0; i < 4; ++i) {
            int rl = wid * 32 + i * 8 + (lane >> 3);
            int bo = (rl * 128 + (lane & 7) * 16) ^ ((rl & 7) << 4);
            bf16x8 vd = *reinterpret_cast<const bf16x8*>(ob + bo);
            *reinterpret_cast<bf16x8*>(
                &C[(size_t)(x * 256 + rl) * 256 + q * 64 + (lane & 7) * 8]) = vd;
        }
    }
}

// ---------------------------------------------------------------------------
// MFMA global attention: K and V both staged in LDS (swizzled); P overlays K.
__global__ __launch_bounds__(256) void global_attn_mfma(const __bf16* __restrict__ Qb,
                                                        const __bf16* __restrict__ Kb,
                                                        const __bf16* __restrict__ Vt,
                                                        __bf16* __restrict__ od) {
    __shared__ __align__(16) char lds[65536];   // [0,32K): K then P; [32K,64K): V
    const int tid = threadIdx.x;
    const int wid = tid >> 6, lane = tid & 63;
    const int bh = blockIdx.x >> 2, qq = blockIdx.x & 3;
    const int b = bh >> 2, h = bh & 3;
    const int qb = qq * 4 + wid;
    const int g = lane >> 4, c = lane & 15;

    // ---- stage K slice (32KB) ----
    {
        const __bf16* kgp = Kb + ((size_t)b * 256) * 256 + h * 64;
        int krow = tid >> 3, ch = tid & 7;
        #pragma unroll
        for (int p = 0; p < 8; ++p) {
            int kk = p * 32 + krow;
            bf16x8 val = *reinterpret_cast<const bf16x8*>(kgp + (size_t)kk * 256 + ch * 8);
            int bo = (kk * 128 + ch * 16) ^ ((kk & 7) << 4);
            *reinterpret_cast<bf16x8*>(lds + bo) = val;
        }
    }
    // ---- stage V slice (32KB), row-major [64][256], swizzled ----
    {
        const bf16x8* vgp = reinterpret_cast<const bf16x8*>(Vt + (size_t)bh * 16384);
        #pragma unroll
        for (int p = 0; p < 8; ++p) {
            int off = p * 256 + tid;
            bf16x8 val = vgp[off];
            int row = off >> 5;
            int colb = (off & 31) * 16;
            int bo = 32768 + ((row * 512 + colb) ^ ((row & 7) << 4));
            *reinterpret_cast<bf16x8*>(lds + bo) = val;
        }
    }
    const __bf16* qptr = Qb + ((size_t)(b * 256 + qb * 16 + c)) * 256 + h * 64 + g * 8;
    bf16x8 aq0 = *reinterpret_cast<const bf16x8*>(qptr);
    bf16x8 aq1 = *reinterpret_cast<const bf16x8*>(qptr + 32);
    __syncthreads();

    // ---- QK^T from LDS ----
    f32x4 S[16];
    #pragma unroll
    for (int jt = 0; jt < 16; ++jt) S[jt] = (f32x4){0.f, 0.f, 0.f, 0.f};
    #pragma unroll
    for (int jt = 0; jt < 16; ++jt) {
        int key = jt * 16 + c;
        int sw = (key & 7) << 4;
        int bo0 = (key * 128 + g * 16) ^ sw;
        int bo1 = (key * 128 + 64 + g * 16) ^ sw;
        bf16x8 bk0 = *reinterpret_cast<const bf16x8*>(lds + bo0);
        bf16x8 bk1 = *reinterpret_cast<const bf16x8*>(lds + bo1);
        S[jt] = __builtin_amdgcn_mfma_f32_16x16x32_bf16(aq0, bk0, S[jt], 0, 0, 0);
        S[jt] = __builtin_amdgcn_mfma_f32_16x16x32_bf16(aq1, bk1, S[jt], 0, 0, 0);
    }

    // ---- softmax over 256 keys ----
    float rmax[4] = {-3e38f, -3e38f, -3e38f, -3e38f};
    #pragma unroll
    for (int jt = 0; jt < 16; ++jt)
        #pragma unroll
        for (int r = 0; r < 4; ++r) {
            float s = S[jt][r] * 0.125f;
            S[jt][r] = s;
            rmax[r] = fmaxf(rmax[r], s);
        }
    #pragma unroll
    for (int r = 0; r < 4; ++r) {
        rmax[r] = fmaxf(rmax[r], __shfl_xor(rmax[r], 1));
        rmax[r] = fmaxf(rmax[r], __shfl_xor(rmax[r], 2));
        rmax[r] = fmaxf(rmax[r], __shfl_xor(rmax[r], 4));
        rmax[r] = fmaxf(rmax[r], __shfl_xor(rmax[r], 8));
    }
    float rsum[4] = {0.f, 0.f, 0.f, 0.f};
    #pragma unroll
    for (int jt = 0; jt < 16; ++jt)
        #pragma unroll
        for (int r = 0; r < 4; ++r) {
            float e = __expf(S[jt][r] - rmax[r]);
            S[jt][r] = e;
            rsum[r] += e;
        }
    #pragma unroll
    for (int r = 0; r < 4; ++r) {
        rsum[r] += __shfl_xor(rsum[r], 1);
        rsum[r] += __shfl_xor(rsum[r], 2);
        rsum[r] += __shfl_xor(rsum[r], 4);
        rsum[r] += __shfl_xor(rsum[r], 8);
    }

    __syncthreads();   // all waves done reading K; overlay P
    char* Pw = lds + wid * 8192;
    #pragma unroll
    for (int jt = 0; jt < 16; ++jt)
        #pragma unroll
        for (int r = 0; r < 4; ++r) {
            int row = g * 4 + r;
            int bo = row * 512 + (jt * 16 + c) * 2;
            bo ^= (row & 7) << 4;
            *reinterpret_cast<__bf16*>(Pw + bo) = (__bf16)S[jt][r];
        }
    __syncthreads();

    // ---- O = P V, both from LDS ----
    f32x4 O[4];
    #pragma unroll
    for (int dt = 0; dt < 4; ++dt) O[dt] = (f32x4){0.f, 0.f, 0.f, 0.f};

    #pragma unroll
    for (int mc = 0; mc < 8; ++mc) {
        int bo = c * 512 + (mc * 32 + g * 8) * 2;
        bo ^= (c & 7) << 4;
        bf16x8 ap = *reinterpret_cast<const bf16x8*>(Pw + bo);
        #pragma unroll
        for (int dt = 0; dt < 4; ++dt) {
            int vrow = dt * 16 + c;
            int vbo = 32768 + ((vrow * 512 + mc * 64 + g * 16) ^ ((vrow & 7) << 4));
            bf16x8 bv = *reinterpret_cast<const bf16x8*>(lds + vbo);
            O[dt] = __builtin_amdgcn_mfma_f32_16x16x32_bf16(ap, bv, O[dt], 0, 0, 0);
        }
    }

    #pragma unroll
    for (int dt = 0; dt < 4; ++dt)
        #pragma unroll
        for (int r = 0; r < 4; ++r) {
            int n = b * 256 + qb * 16 + g * 4 + r;
            int col = h * 64 + dt * 16 + c;
            od[(size_t)n * 256 + col] = (__bf16)(O[dt][r] / rsum[r]);
        }
}

// ---------------------------------------------------------------------------
// Merged: local attention (blocks [0,nlb)) + go GEMM (blocks [nlb, nlb+nb_go)).
__global__ __launch_bounds__(256) void lattn_go(
        const __bf16* __restrict__ ql, const __bf16* __restrict__ kl,
        const __bf16* __restrict__ vl,
        const int* __restrict__ bucket, const int* __restrict__ deg,
        __bf16* __restrict__ aggb,
        const __bf16* __restrict__ od, const __bf16* __restrict__ Wp,
        const float* __restrict__ go_b, __bf16* __restrict__ od2b,
        int nlb, int M, int tot) {
    __shared__ __align__(16) __bf16 wlds[16384];
    int bid = blockIdx.x;
    const int wid = threadIdx.x >> 6, lane = threadIdx.x & 63;
    const int g = lane >> 4, c = lane & 15;

    if (bid >= nlb) {
        // ---- go GEMM path ----
        int gb = bid - nlb;
        const int gxg = M >> 6;
        const int bx = gb % gxg, by = gb / gxg;
        {
            const __bf16* gs = Wp + (size_t)by * 16384;
            #pragma unroll
            for (int it = 0; it < 8; ++it) {
                int chunk = it * 256 + threadIdx.x;
                GLOAD_LDS16(gs + chunk * 8, wlds + chunk * 8);
            }
        }
        const int row0 = bx * 64 + wid * 16;
        const __bf16* arow = od + (size_t)(row0 + c) * 256 + g * 8;
        bf16x8 af = *reinterpret_cast<const bf16x8*>(arow);

        f32x4 acc[4];
        #pragma unroll
        for (int jt = 0; jt < 4; ++jt) acc[jt] = (f32x4){0.f, 0.f, 0.f, 0.f};

        const char* wl = reinterpret_cast<const char*>(wlds) + lane * 16;
        __syncthreads();
        #pragma unroll
        for (int ks = 0; ks < 8; ++ks) {
            bf16x8 nf;
            if (ks < 7) nf = *reinterpret_cast<const bf16x8*>(arow + (ks + 1) * 32);
            #pragma unroll
            for (int jt = 0; jt < 4; ++jt) {
                bf16x8 bf_ = *reinterpret_cast<const bf16x8*>(wl + (jt * 8 + ks) * 1024);
                acc[jt] = __builtin_amdgcn_mfma_f32_16x16x32_bf16(bf_, af, acc[jt], 0, 0, 0);
            }
            af = nf;
        }
        int row = row0 + c;
        #pragma unroll
        for (int jt = 0; jt < 4; ++jt) {
            int col0 = by * 64 + jt * 16 + g * 4;
            float4 bv = *reinterpret_cast<const float4*>(go_b + col0);
            bf16x4 st;
            st[0] = (__bf16)(acc[jt][0] + bv.x);
            st[1] = (__bf16)(acc[jt][1] + bv.y);
            st[2] = (__bf16)(acc[jt][2] + bv.z);
            st[3] = (__bf16)(acc[jt][3] + bv.w);
            *reinterpret_cast<bf16x4*>(&od2b[(size_t)row * 256 + col0]) = st;
        }
        return;
    }

    // ---- local attention path (XCD-contiguous swizzle within [0,nlb)) ----
    int lb = (bid & 7) * (nlb >> 3) + (bid >> 3);
    int w = (lb * 256 + (int)threadIdx.x) >> 6;
    if (w >= tot) return;
    const int t = w;
    const int cc = c;

    float qf[16];
    {
        const ushort4* qr = reinterpret_cast<const ushort4*>(ql + (size_t)t * 256);
        #pragma unroll
        for (int u = 0; u < 4; ++u) {
            ushort4 qv = qr[cc * 4 + u];
            qf[u * 4 + 0] = us2f(qv.x); qf[u * 4 + 1] = us2f(qv.y);
            qf[u * 4 + 2] = us2f(qv.z); qf[u * 4 + 3] = us2f(qv.w);
        }
    }

    int dg = deg[t];
    if (dg > BCAP) dg = BCAP;
    const int* bkt = bucket + (size_t)t * BCAP;
    float M_ = -3.0e38f, den = 0.f;
    float a0 = 0.f, a1 = 0.f, a2 = 0.f, a3 = 0.f;

    for (int i0 = 0; i0 < dg; i0 += 4) {
        bool valid = (i0 + g) < dg;
        int s = valid ? bkt[i0 + g] : 0;

        float p = 0.f;
        const ushort4* kr = reinterpret_cast<const ushort4*>(kl + (size_t)s * 256);
        #pragma unroll
        for (int u = 0; u < 4; ++u) {
            ushort4 kv = kr[cc * 4 + u];
            p += qf[u * 4 + 0] * us2f(kv.x) + qf[u * 4 + 1] * us2f(kv.y)
               + qf[u * 4 + 2] * us2f(kv.z) + qf[u * 4 + 3] * us2f(kv.w);
        }
        p += __shfl_xor(p, 1); p += __shfl_xor(p, 2);
        p += __shfl_xor(p, 4); p += __shfl_xor(p, 8);

        float lg[4]; int sj[4];
        #pragma unroll
        for (int jj = 0; jj < 4; ++jj) {
            float pj = __shfl(p, jj * 16);
            int   ssj = __shfl(s, jj * 16);
            bool vj = (i0 + jj) < dg;
            lg[jj] = vj ? pj * 0.0625f : -3.0e38f;
            sj[jj] = vj ? ssj : 0;
        }

        float nM = fmaxf(fmaxf(fmaxf(lg[0], lg[1]), fmaxf(lg[2], lg[3])), M_);
        float sc = __expf(M_ - nM);
        float ex[4];
        #pragma unroll
        for (int jj = 0; jj < 4; ++jj) ex[jj] = __expf(lg[jj] - nM);

        float s0 = 0.f, s1 = 0.f, s2 = 0.f, s3 = 0.f;
        #pragma unroll
        for (int jj = 0; jj < 4; ++jj) {
            ushort4 vv = reinterpret_cast<const ushort4*>(vl + (size_t)sj[jj] * 256)[lane];
            s0 += ex[jj] * us2f(vv.x); s1 += ex[jj] * us2f(vv.y);
            s2 += ex[jj] * us2f(vv.z); s3 += ex[jj] * us2f(vv.w);
        }
        a0 = a0 * sc + s0; a1 = a1 * sc + s1;
        a2 = a2 * sc + s2; a3 = a3 * sc + s3;
        den = den * sc + ex[0] + ex[1] + ex[2] + ex[3];
        M_ = nM;
    }
    float inv = (dg > 0) ? 1.0f / den : 0.0f;
    bf16x4 o;
    o[0] = (__bf16)(a0 * inv); o[1] = (__bf16)(a1 * inv);
    o[2] = (__bf16)(a2 * inv); o[3] = (__bf16)(a3 * inv);
    reinterpret_cast<bf16x4*>(aggb + (size_t)t * 256)[lane] = o;
}

// ---------------------------------------------------------------------------
// fusion + LayerNorm, f32 output. one wave per row; lane owns 4 consecutive cols.
__global__ __launch_bounds__(256) void fuse_ln(const float* __restrict__ x,
                                               const __bf16* __restrict__ aggb,
                                               const __bf16* __restrict__ skipb,
                                               const __bf16* __restrict__ od2b,
                                               const float* __restrict__ wl_p,
                                               const float* __restrict__ wg_p,
                                               const float* __restrict__ gam,
                                               const float* __restrict__ bet,
                                               float* __restrict__ out, int tot) {
    int w = (blockIdx.x * 256 + threadIdx.x) >> 6;
    int lane = threadIdx.x & 63;
    if (w >= tot) return;
    const float wl = wl_p[0], wg = wg_p[0];
    size_t base = (size_t)w * 256;
    float4 xv = reinterpret_cast<const float4*>(x + base)[lane];
    ushort4 ag = reinterpret_cast<const ushort4*>(aggb + base)[lane];
    ushort4 sk = reinterpret_cast<const ushort4*>(skipb + base)[lane];
    ushort4 o2 = reinterpret_cast<const ushort4*>(od2b + base)[lane];
    float v[4];
    v[0] = wl * (us2f(ag.x) + us2f(sk.x)) + wg * (us2f(o2.x) + xv.x) + xv.x;
    v[1] = wl * (us2f(ag.y) + us2f(sk.y)) + wg * (us2f(o2.y) + xv.y) + xv.y;
    v[2] = wl * (us2f(ag.z) + us2f(sk.z)) + wg * (us2f(o2.z) + xv.z) + xv.z;
    v[3] = wl * (us2f(ag.w) + us2f(sk.w)) + wg * (us2f(o2.w) + xv.w) + xv.w;

    float s = v[0] + v[1] + v[2] + v[3];
    #pragma unroll
    for (int off = 32; off; off >>= 1) s += __shfl_xor(s, off);
    float mu = s * (1.0f / 256.0f);
    float e[4], ss = 0.f;
    #pragma unroll
    for (int j = 0; j < 4; ++j) { e[j] = v[j] - mu; ss += e[j] * e[j]; }
    #pragma unroll
    for (int off = 32; off; off >>= 1) ss += __shfl_xor(ss, off);
    float rstd = rsqrtf(ss * (1.0f / 256.0f) + 1e-5f);
    float4 go;
    int c0 = lane * 4;
    go.x = e[0] * rstd * gam[c0 + 0] + bet[c0 + 0];
    go.y = e[1] * rstd * gam[c0 + 1] + bet[c0 + 1];
    go.z = e[2] * rstd * gam[c0 + 2] + bet[c0 + 2];
    go.w = e[3] * rstd * gam[c0 + 3] + bet[c0 + 3];
    reinterpret_cast<float4*>(out + base)[lane] = go;
}

// ---------------------------------------------------------------------------
extern "C" void kernel_launch(void* const* d_in, const int* in_sizes, int n_in,
                              void* d_out, int out_size, void* d_ws, size_t ws_size,
                              hipStream_t stream) {
    const float* x    = (const float*)d_in[0];
    const int*   ei   = (const int*)d_in[1];
    const float* lq_w = (const float*)d_in[3];  const float* lq_b = (const float*)d_in[4];
    const float* lk_w = (const float*)d_in[5];  const float* lk_b = (const float*)d_in[6];
    const float* lv_w = (const float*)d_in[7];  const float* lv_b = (const float*)d_in[8];
    const float* ls_w = (const float*)d_in[9];  const float* ls_b = (const float*)d_in[10];
    const float* gq_w = (const float*)d_in[11]; const float* gq_b = (const float*)d_in[12];
    const float* gk_w = (const float*)d_in[13]; const float* gk_b = (const float*)d_in[14];
    const float* gv_w = (const float*)d_in[15]; const float* gv_b = (const float*)d_in[16];
    const float* go_w = (const float*)d_in[17]; const float* go_b = (const float*)d_in[18];
    const float* wl   = (const float*)d_in[19]; const float* wg   = (const float*)d_in[20];
    const float* ln_g = (const float*)d_in[21]; const float* ln_b = (const float*)d_in[22];

    const int TOT = in_sizes[0] / D_DIM;
    const int E = in_sizes[1] / 2;
    const int B = TOT / NPG;
    const size_t S = (size_t)TOT * D_DIM;

    // workspace layout: 11 x S bf16 + wt + bucket/deg
    __bf16* xpk   = (__bf16*)d_ws;      // S (fragment-packed x)
    __bf16* qg    = xpk + S;
    __bf16* kg    = qg + S;
    __bf16* aggb  = kg + S;             // S (local-attn output, bf16)
    __bf16* ql    = aggb + S;
    __bf16* kl    = ql + S;
    __bf16* vl    = kl + S;
    __bf16* skipb = vl + S;
    __bf16* od2b  = skipb + S;
    __bf16* Vt    = od2b + S;           // S (written directly by proj_csr)
    __bf16* od    = Vt + S;             // S
    __bf16* wt    = od + S;             // 8 x 65536 (fragment-packed)
    int* bucket = (int*)(wt + 8 * 65536);   // TOT*BCAP
    int* deg    = bucket + (size_t)TOT * BCAP;

    // ---- 1. merged prep (pack x, pack W, zero deg) ----
    const int nb1 = TOT / 16;
    const int nbz = (TOT + 255) / 256;
    prep_misc<<<nb1 + 128 + nbz, 256, 0, stream>>>(x, xpk,
        gq_w, gk_w, gv_w, go_w, lq_w, lk_w, lv_w, ls_w, wt, deg, nb1, TOT);

    // ---- 2. fused 7-projection GEMM + edge-bucket build ----
    const int nb_gemm = (TOT / 256) * 28;
    const int nb_edge = (E + 511) / 512;
    proj_csr<<<nb_gemm + nb_edge, 512, 0, stream>>>(xpk, wt,
        gq_b, gk_b, gv_b, lq_b, lk_b, lv_b, ls_b,
        qg, kg, Vt, ql, kl, vl, skipb,
        ei, bucket, deg, E, nb_gemm, TOT);

    // ---- 3. global attention ----
    global_attn_mfma<<<B * HEADS * 4, 256, 0, stream>>>(qg, kg, Vt, od);

    // ---- 4. merged local attention + go GEMM ----
    __bf16* wt_go = wt + 3 * 65536;
    const int nlb = TOT / 4;
    const int nb_go = (TOT / 64) * 4;
    lattn_go<<<nlb + nb_go, 256, 0, stream>>>(ql, kl, vl, bucket, deg, aggb,
                                              od, wt_go, go_b, od2b,
                                              nlb, TOT, TOT);

    // ---- 5. fuse + layernorm -> f32 out ----
    fuse_ln<<<(TOT + 3) / 4, 256, 0, stream>>>(x, aggb, skipb, od2b, wl, wg, ln_g, ln_b,
                                               (float*)d_out, TOT);
}

// Round 19
// 106.980 us; speedup vs baseline: 1.3739x; 1.0261x over previous
//
#include <hip/hip_runtime.h>
#include <hip/hip_bf16.h>

#define D_DIM 256
#define NPG   256
#define HEADS 4
#define HD    64
#define BCAP  64   // per-node edge bucket capacity (deg ~ Poisson(16))

typedef __bf16 bf16x8 __attribute__((ext_vector_type(8)));
typedef __bf16 bf16x4 __attribute__((ext_vector_type(4)));
typedef float  f32x4  __attribute__((ext_vector_type(4)));

__device__ inline float us2f(unsigned short u) {
    union { unsigned int i; float f; } cv; cv.i = ((unsigned int)u) << 16; return cv.f;
}
__device__ inline float bl(unsigned int w) {
    union { unsigned int i; float f; } c; c.i = w << 16; return c.f;
}
__device__ inline float bh(unsigned int w) {
    union { unsigned int i; float f; } c; c.i = w & 0xffff0000u; return c.f;
}

// async global->LDS, 16B per lane (dest = wave-uniform base + lane*16)
#define GLOAD_LDS16(g, l) __builtin_amdgcn_global_load_lds(                    \
    (const __attribute__((address_space(1))) void*)(g),                        \
    (__attribute__((address_space(3))) void*)(l), 16, 0, 0)

// ---------------------------------------------------------------------------
// merged prep: [0,nb1) convert_pack_x | [nb1,nb1+128) transpose_pack_w8 |
//              [nb1+128, ...) zero deg
__global__ __launch_bounds__(256) void prep_misc(const float* __restrict__ x,
                                                 __bf16* __restrict__ xpk,
        const float* w0, const float* w1, const float* w2, const float* w3,
        const float* w4, const float* w5, const float* w6, const float* w7,
        __bf16* __restrict__ wt, int* __restrict__ zeros, int nb1, int tot) {
    __shared__ __bf16 tile[256][16];
    int bid = blockIdx.x;
    const int t = threadIdx.x;
    if (bid < nb1) {
        const int rt = bid;
        const int ks = t >> 5;
        #pragma unroll
        for (int h2 = 0; h2 < 2; ++h2) {
            int lane = (t & 31) * 2 + h2;
            int row = rt * 16 + (lane & 15);
            int col = ks * 32 + (lane >> 4) * 8;
            const float4* src = reinterpret_cast<const float4*>(x + (size_t)row * 256 + col);
            float4 f0 = src[0], f1 = src[1];
            __bf16* o = xpk + ((size_t)(rt * 8 + ks) * 64 + lane) * 8;
            o[0] = (__bf16)f0.x; o[1] = (__bf16)f0.y; o[2] = (__bf16)f0.z; o[3] = (__bf16)f0.w;
            o[4] = (__bf16)f1.x; o[5] = (__bf16)f1.y; o[6] = (__bf16)f1.z; o[7] = (__bf16)f1.w;
        }
        return;
    }
    bid -= nb1;
    if (bid < 128) {
        const float* Ws[8] = {w0, w1, w2, w3, w4, w5, w6, w7};
        const int jt2 = bid & 15, wsel = bid >> 4;
        const float* W = Ws[wsel];
        const float4* wr = reinterpret_cast<const float4*>(W + (size_t)t * 256 + jt2 * 16);
        #pragma unroll
        for (int u = 0; u < 4; ++u) {
            float4 f = wr[u];
            tile[t][u * 4 + 0] = (__bf16)f.x; tile[t][u * 4 + 1] = (__bf16)f.y;
            tile[t][u * 4 + 2] = (__bf16)f.z; tile[t][u * 4 + 3] = (__bf16)f.w;
        }
        __syncthreads();
        __bf16* out = wt + ((size_t)wsel * 16 + jt2) * 4096;
        #pragma unroll
        for (int u = 0; u < 16; ++u) {
            int e = t * 16 + u;
            int ks = e >> 9, lane = (e >> 3) & 63, i = e & 7;
            int g = lane >> 4, c = lane & 15;
            int k = ks * 32 + g * 8 + i;
            out[e] = tile[k][c];
        }
        return;
    }
    bid -= 128;
    int i = bid * 256 + t;
    if (i < tot) zeros[i] = 0;
}

// ---------------------------------------------------------------------------
// Fused: 7-projection GEMM (blocks [0,nb_gemm)) + edge-bucket build (rest).
// XCD-swizzled x; VGPR-lean A loads; LDS-bounce store epilogue (j!=2).
__global__ __launch_bounds__(512) void proj_csr(const __bf16* __restrict__ xpk,
                                                const __bf16* __restrict__ wt,
        const float* b_gq, const float* b_gk, const float* b_gv,
        const float* b_lq, const float* b_lk, const float* b_lv, const float* b_ls,
        __bf16* o_gq, __bf16* o_gk, __bf16* Vt,
        __bf16* o_lq, __bf16* o_lk, __bf16* o_lv, __bf16* o_ls,
        const int* __restrict__ ei_raw, int* __restrict__ bucket,
        int* __restrict__ deg, int E, int nb_gemm, int M) {
    __shared__ __align__(16) __bf16 wlds[16384];   // W quarter; later C-tile bounce
    int bid = blockIdx.x;
    if (bid >= nb_gemm) {
        int v = ei_raw[2 * (threadIdx.x & 63) + 1];
        unsigned long long nz = __ballot(v != 0);
        bool is64 = (nz == 0ULL);
        int e = (bid - nb_gemm) * 512 + threadIdx.x;
        if (e >= E) return;
        int s, d;
        if (is64) { s = ei_raw[2 * e]; d = ei_raw[2 * (E + e)]; }
        else      { s = ei_raw[e];     d = ei_raw[E + e]; }
        int p = atomicAdd(&deg[d], 1);
        if (p < BCAP) bucket[d * BCAP + p] = s;
        return;
    }
    const int gx = M >> 8;
    const int cpx = gx >> 3;
    const int xcd = bid & 7;
    const int local = bid >> 3;
    const int x = xcd * cpx + (local % cpx);
    const int y = local / cpx;
    const int j = y >> 2;
    const int q = y & 3;
    const int wsel = (j < 3) ? j : j + 1;
    const float* bias = (j == 0) ? b_gq : (j == 1) ? b_gk : (j == 2) ? b_gv :
                        (j == 3) ? b_lq : (j == 4) ? b_lk : (j == 5) ? b_lv : b_ls;
    __bf16* C = (j == 0) ? o_gq : (j == 1) ? o_gk : (j == 2) ? nullptr :
                (j == 3) ? o_lq : (j == 4) ? o_lk : (j == 5) ? o_lv : o_ls;

    {
        const __bf16* gs = wt + (size_t)wsel * 65536 + (size_t)q * 16384;
        #pragma unroll
        for (int it = 0; it < 4; ++it) {
            int ch = it * 512 + threadIdx.x;
            GLOAD_LDS16(gs + ch * 8, wlds + ch * 8);
        }
    }

    const int wid = threadIdx.x >> 6, lane = threadIdx.x & 63;
    const int g = lane >> 4, c = lane & 15;
    const int rt0 = x * 16 + wid * 2;
    const char* wl = reinterpret_cast<const char*>(wlds) + lane * 16;

    __syncthreads();

    f32x4 acc[2][4];
    #pragma unroll
    for (int h = 0; h < 2; ++h)
        #pragma unroll
        for (int jt = 0; jt < 4; ++jt) acc[h][jt] = (f32x4){0.f, 0.f, 0.f, 0.f};

    const __bf16* ap0 = xpk + ((size_t)rt0 * 8) * 512 + lane * 8;
    const __bf16* ap1 = ap0 + 8 * 512;
    #pragma unroll
    for (int ks = 0; ks < 8; ++ks) {
        bf16x8 af0 = *reinterpret_cast<const bf16x8*>(ap0 + ks * 512);
        bf16x8 af1 = *reinterpret_cast<const bf16x8*>(ap1 + ks * 512);
        #pragma unroll
        for (int jt = 0; jt < 4; ++jt) {
            bf16x8 bf_ = *reinterpret_cast<const bf16x8*>(wl + (jt * 8 + ks) * 1024);
            acc[0][jt] = __builtin_amdgcn_mfma_f32_16x16x32_bf16(bf_, af0, acc[0][jt], 0, 0, 0);
            acc[1][jt] = __builtin_amdgcn_mfma_f32_16x16x32_bf16(bf_, af1, acc[1][jt], 0, 0, 0);
        }
    }

    if (j == 2) {
        #pragma unroll
        for (int h = 0; h < 2; ++h) {
            int m = (rt0 + h) * 16 + c;
            int b = m >> 8, mm = m & 255;
            #pragma unroll
            for (int jt = 0; jt < 4; ++jt) {
                int col0 = q * 64 + jt * 16 + g * 4;
                float4 bv = *reinterpret_cast<const float4*>(bias + col0);
                Vt[(size_t)(b * 256 + col0 + 0) * 256 + mm] = (__bf16)(acc[h][jt][0] + bv.x);
                Vt[(size_t)(b * 256 + col0 + 1) * 256 + mm] = (__bf16)(acc[h][jt][1] + bv.y);
                Vt[(size_t)(b * 256 + col0 + 2) * 256 + mm] = (__bf16)(acc[h][jt][2] + bv.z);
                Vt[(size_t)(b * 256 + col0 + 3) * 256 + mm] = (__bf16)(acc[h][jt][3] + bv.w);
            }
        }
    } else {
        __syncthreads();
        char* ob = reinterpret_cast<char*>(wlds);
        #pragma unroll
        for (int h = 0; h < 2; ++h) {
            int row_local = wid * 32 + h * 16 + c;
            int swz = (row_local & 7) << 4;
            #pragma unroll
            for (int jt = 0; jt < 4; ++jt) {
                int col2 = jt * 16 + g * 4;
                float4 bv = *reinterpret_cast<const float4*>(bias + q * 64 + col2);
                bf16x4 st;
                st[0] = (__bf16)(acc[h][jt][0] + bv.x);
                st[1] = (__bf16)(acc[h][jt][1] + bv.y);
                st[2] = (__bf16)(acc[h][jt][2] + bv.z);
                st[3] = (__bf16)(acc[h][jt][3] + bv.w);
                int bo = (row_local * 128 + col2 * 2) ^ swz;
                *reinterpret_cast<bf16x4*>(ob + bo) = st;
            }
        }
        __syncthreads();
        #pragma unroll
        for (int i = 0; i < 4; ++i) {
            int rl = wid * 32 + i * 8 + (lane >> 3);
            int bo = (rl * 128 + (lane & 7) * 16) ^ ((rl & 7) << 4);
            bf16x8 vd = *reinterpret_cast<const bf16x8*>(ob + bo);
            *reinterpret_cast<bf16x8*>(
                &C[(size_t)(x * 256 + rl) * 256 + q * 64 + (lane & 7) * 8]) = vd;
        }
    }
}

// ---------------------------------------------------------------------------
// MFMA global attention: K and V both staged in LDS (swizzled); P overlays K.
__global__ __launch_bounds__(256) void global_attn_mfma(const __bf16* __restrict__ Qb,
                                                        const __bf16* __restrict__ Kb,
                                                        const __bf16* __restrict__ Vt,
                                                        __bf16* __restrict__ od) {
    __shared__ __align__(16) char lds[65536];
    const int tid = threadIdx.x;
    const int wid = tid >> 6, lane = tid & 63;
    const int bh = blockIdx.x >> 2, qq = blockIdx.x & 3;
    const int b = bh >> 2, h = bh & 3;
    const int qb = qq * 4 + wid;
    const int g = lane >> 4, c = lane & 15;

    {
        const __bf16* kgp = Kb + ((size_t)b * 256) * 256 + h * 64;
        int krow = tid >> 3, ch = tid & 7;
        #pragma unroll
        for (int p = 0; p < 8; ++p) {
            int kk = p * 32 + krow;
            bf16x8 val = *reinterpret_cast<const bf16x8*>(kgp + (size_t)kk * 256 + ch * 8);
            int bo = (kk * 128 + ch * 16) ^ ((kk & 7) << 4);
            *reinterpret_cast<bf16x8*>(lds + bo) = val;
        }
    }
    {
        const bf16x8* vgp = reinterpret_cast<const bf16x8*>(Vt + (size_t)bh * 16384);
        #pragma unroll
        for (int p = 0; p < 8; ++p) {
            int off = p * 256 + tid;
            bf16x8 val = vgp[off];
            int row = off >> 5;
            int colb = (off & 31) * 16;
            int bo = 32768 + ((row * 512 + colb) ^ ((row & 7) << 4));
            *reinterpret_cast<bf16x8*>(lds + bo) = val;
        }
    }
    const __bf16* qptr = Qb + ((size_t)(b * 256 + qb * 16 + c)) * 256 + h * 64 + g * 8;
    bf16x8 aq0 = *reinterpret_cast<const bf16x8*>(qptr);
    bf16x8 aq1 = *reinterpret_cast<const bf16x8*>(qptr + 32);
    __syncthreads();

    f32x4 S[16];
    #pragma unroll
    for (int jt = 0; jt < 16; ++jt) S[jt] = (f32x4){0.f, 0.f, 0.f, 0.f};
    #pragma unroll
    for (int jt = 0; jt < 16; ++jt) {
        int key = jt * 16 + c;
        int sw = (key & 7) << 4;
        int bo0 = (key * 128 + g * 16) ^ sw;
        int bo1 = (key * 128 + 64 + g * 16) ^ sw;
        bf16x8 bk0 = *reinterpret_cast<const bf16x8*>(lds + bo0);
        bf16x8 bk1 = *reinterpret_cast<const bf16x8*>(lds + bo1);
        S[jt] = __builtin_amdgcn_mfma_f32_16x16x32_bf16(aq0, bk0, S[jt], 0, 0, 0);
        S[jt] = __builtin_amdgcn_mfma_f32_16x16x32_bf16(aq1, bk1, S[jt], 0, 0, 0);
    }

    float rmax[4] = {-3e38f, -3e38f, -3e38f, -3e38f};
    #pragma unroll
    for (int jt = 0; jt < 16; ++jt)
        #pragma unroll
        for (int r = 0; r < 4; ++r) {
            float s = S[jt][r] * 0.125f;
            S[jt][r] = s;
            rmax[r] = fmaxf(rmax[r], s);
        }
    #pragma unroll
    for (int r = 0; r < 4; ++r) {
        rmax[r] = fmaxf(rmax[r], __shfl_xor(rmax[r], 1));
        rmax[r] = fmaxf(rmax[r], __shfl_xor(rmax[r], 2));
        rmax[r] = fmaxf(rmax[r], __shfl_xor(rmax[r], 4));
        rmax[r] = fmaxf(rmax[r], __shfl_xor(rmax[r], 8));
    }
    float rsum[4] = {0.f, 0.f, 0.f, 0.f};
    #pragma unroll
    for (int jt = 0; jt < 16; ++jt)
        #pragma unroll
        for (int r = 0; r < 4; ++r) {
            float e = __expf(S[jt][r] - rmax[r]);
            S[jt][r] = e;
            rsum[r] += e;
        }
    #pragma unroll
    for (int r = 0; r < 4; ++r) {
        rsum[r] += __shfl_xor(rsum[r], 1);
        rsum[r] += __shfl_xor(rsum[r], 2);
        rsum[r] += __shfl_xor(rsum[r], 4);
        rsum[r] += __shfl_xor(rsum[r], 8);
    }

    __syncthreads();
    char* Pw = lds + wid * 8192;
    #pragma unroll
    for (int jt = 0; jt < 16; ++jt)
        #pragma unroll
        for (int r = 0; r < 4; ++r) {
            int row = g * 4 + r;
            int bo = row * 512 + (jt * 16 + c) * 2;
            bo ^= (row & 7) << 4;
            *reinterpret_cast<__bf16*>(Pw + bo) = (__bf16)S[jt][r];
        }
    __syncthreads();

    f32x4 O[4];
    #pragma unroll
    for (int dt = 0; dt < 4; ++dt) O[dt] = (f32x4){0.f, 0.f, 0.f, 0.f};

    #pragma unroll
    for (int mc = 0; mc < 8; ++mc) {
        int bo = c * 512 + (mc * 32 + g * 8) * 2;
        bo ^= (c & 7) << 4;
        bf16x8 ap = *reinterpret_cast<const bf16x8*>(Pw + bo);
        #pragma unroll
        for (int dt = 0; dt < 4; ++dt) {
            int vrow = dt * 16 + c;
            int vbo = 32768 + ((vrow * 512 + mc * 64 + g * 16) ^ ((vrow & 7) << 4));
            bf16x8 bv = *reinterpret_cast<const bf16x8*>(lds + vbo);
            O[dt] = __builtin_amdgcn_mfma_f32_16x16x32_bf16(ap, bv, O[dt], 0, 0, 0);
        }
    }

    #pragma unroll
    for (int dt = 0; dt < 4; ++dt)
        #pragma unroll
        for (int r = 0; r < 4; ++r) {
            int n = b * 256 + qb * 16 + g * 4 + r;
            int col = h * 64 + dt * 16 + c;
            od[(size_t)n * 256 + col] = (__bf16)(O[dt][r] / rsum[r]);
        }
}

// ---------------------------------------------------------------------------
// Merged: local attention (blocks [0,nlb)) + go GEMM (blocks [nlb, nlb+nb_go)).
// Local path v3: bucket in registers, 8-edge chunks, K+V loads issued together.
__global__ __launch_bounds__(256) void lattn_go(
        const __bf16* __restrict__ ql, const __bf16* __restrict__ kl,
        const __bf16* __restrict__ vl,
        const int* __restrict__ bucket, const int* __restrict__ deg,
        __bf16* __restrict__ aggb,
        const __bf16* __restrict__ od, const __bf16* __restrict__ Wp,
        const float* __restrict__ go_b, __bf16* __restrict__ od2b,
        int nlb, int M, int tot) {
    __shared__ __align__(16) __bf16 wlds[16384];
    int bid = blockIdx.x;
    const int wid = threadIdx.x >> 6, lane = threadIdx.x & 63;
    const int g = lane >> 4, c = lane & 15;

    if (bid >= nlb) {
        // ---- go GEMM path ----
        int gb = bid - nlb;
        const int gxg = M >> 6;
        const int bx = gb % gxg, by = gb / gxg;
        {
            const __bf16* gs = Wp + (size_t)by * 16384;
            #pragma unroll
            for (int it = 0; it < 8; ++it) {
                int chunk = it * 256 + threadIdx.x;
                GLOAD_LDS16(gs + chunk * 8, wlds + chunk * 8);
            }
        }
        const int row0 = bx * 64 + wid * 16;
        const __bf16* arow = od + (size_t)(row0 + c) * 256 + g * 8;
        bf16x8 af = *reinterpret_cast<const bf16x8*>(arow);

        f32x4 acc[4];
        #pragma unroll
        for (int jt = 0; jt < 4; ++jt) acc[jt] = (f32x4){0.f, 0.f, 0.f, 0.f};

        const char* wl = reinterpret_cast<const char*>(wlds) + lane * 16;
        __syncthreads();
        #pragma unroll
        for (int ks = 0; ks < 8; ++ks) {
            bf16x8 nf;
            if (ks < 7) nf = *reinterpret_cast<const bf16x8*>(arow + (ks + 1) * 32);
            #pragma unroll
            for (int jt = 0; jt < 4; ++jt) {
                bf16x8 bf_ = *reinterpret_cast<const bf16x8*>(wl + (jt * 8 + ks) * 1024);
                acc[jt] = __builtin_amdgcn_mfma_f32_16x16x32_bf16(bf_, af, acc[jt], 0, 0, 0);
            }
            af = nf;
        }
        int row = row0 + c;
        #pragma unroll
        for (int jt = 0; jt < 4; ++jt) {
            int col0 = by * 64 + jt * 16 + g * 4;
            float4 bv = *reinterpret_cast<const float4*>(go_b + col0);
            bf16x4 st;
            st[0] = (__bf16)(acc[jt][0] + bv.x);
            st[1] = (__bf16)(acc[jt][1] + bv.y);
            st[2] = (__bf16)(acc[jt][2] + bv.z);
            st[3] = (__bf16)(acc[jt][3] + bv.w);
            *reinterpret_cast<bf16x4*>(&od2b[(size_t)row * 256 + col0]) = st;
        }
        return;
    }

    // ---- local attention path v3 ----
    int lb = (bid & 7) * (nlb >> 3) + (bid >> 3);
    int w = (lb * 256 + (int)threadIdx.x) >> 6;
    if (w >= tot) return;
    const int t = w;
    const int g8 = lane >> 3;   // edge within 8-edge chunk
    const int c8 = lane & 7;    // 32-elem group within row

    // full bucket in one register (64 slots, 1/lane)
    int bktreg = bucket[(size_t)t * BCAP + lane];
    int dg = deg[t];
    if (dg > BCAP) dg = BCAP;

    // q row: 32 f32 elems per lane for the dot phase
    float qf[32];
    {
        const uint4* qr = reinterpret_cast<const uint4*>(ql + (size_t)t * 256) + c8 * 4;
        #pragma unroll
        for (int u = 0; u < 4; ++u) {
            uint4 qv = qr[u];
            qf[u * 8 + 0] = bl(qv.x); qf[u * 8 + 1] = bh(qv.x);
            qf[u * 8 + 2] = bl(qv.y); qf[u * 8 + 3] = bh(qv.y);
            qf[u * 8 + 4] = bl(qv.z); qf[u * 8 + 5] = bh(qv.z);
            qf[u * 8 + 6] = bl(qv.w); qf[u * 8 + 7] = bh(qv.w);
        }
    }

    float M_ = -3.0e38f, den = 0.f;
    float a0 = 0.f, a1 = 0.f, a2 = 0.f, a3 = 0.f;

    for (int i0 = 0; i0 < dg; i0 += 8) {
        // addresses from register shuffles; K + V loads all issued together
        bool vK = (i0 + g8) < dg;
        int sK = __shfl(bktreg, i0 + g8);
        sK = vK ? sK : 0;
        int sj[8];
        #pragma unroll
        for (int jj = 0; jj < 8; ++jj) {
            int sv = __shfl(bktreg, i0 + jj);
            sj[jj] = ((i0 + jj) < dg) ? sv : 0;
        }
        const uint4* kr = reinterpret_cast<const uint4*>(kl + (size_t)sK * 256) + c8 * 4;
        uint4 kv[4];
        #pragma unroll
        for (int u = 0; u < 4; ++u) kv[u] = kr[u];
        ushort4 vv[8];
        #pragma unroll
        for (int jj = 0; jj < 8; ++jj)
            vv[jj] = reinterpret_cast<const ushort4*>(vl + (size_t)sj[jj] * 256)[lane];

        // dot over 32 elems/lane, reduce across 8 lanes
        float p = 0.f;
        #pragma unroll
        for (int u = 0; u < 4; ++u) {
            p += qf[u * 8 + 0] * bl(kv[u].x) + qf[u * 8 + 1] * bh(kv[u].x)
               + qf[u * 8 + 2] * bl(kv[u].y) + qf[u * 8 + 3] * bh(kv[u].y)
               + qf[u * 8 + 4] * bl(kv[u].z) + qf[u * 8 + 5] * bh(kv[u].z)
               + qf[u * 8 + 6] * bl(kv[u].w) + qf[u * 8 + 7] * bh(kv[u].w);
        }
        p += __shfl_xor(p, 1); p += __shfl_xor(p, 2); p += __shfl_xor(p, 4);

        float lg[8];
        #pragma unroll
        for (int jj = 0; jj < 8; ++jj) {
            float pj = __shfl(p, jj * 8);
            lg[jj] = ((i0 + jj) < dg) ? pj * 0.0625f : -3.0e38f;
        }
        float nM = M_;
        #pragma unroll
        for (int jj = 0; jj < 8; ++jj) nM = fmaxf(nM, lg[jj]);
        float sc = __expf(M_ - nM);
        float ex[8];
        float esum = 0.f;
        #pragma unroll
        for (int jj = 0; jj < 8; ++jj) { ex[jj] = __expf(lg[jj] - nM); esum += ex[jj]; }

        float s0 = 0.f, s1 = 0.f, s2 = 0.f, s3 = 0.f;
        #pragma unroll
        for (int jj = 0; jj < 8; ++jj) {
            s0 += ex[jj] * us2f(vv[jj].x); s1 += ex[jj] * us2f(vv[jj].y);
            s2 += ex[jj] * us2f(vv[jj].z); s3 += ex[jj] * us2f(vv[jj].w);
        }
        a0 = a0 * sc + s0; a1 = a1 * sc + s1;
        a2 = a2 * sc + s2; a3 = a3 * sc + s3;
        den = den * sc + esum;
        M_ = nM;
    }
    float inv = (dg > 0) ? 1.0f / den : 0.0f;
    bf16x4 o;
    o[0] = (__bf16)(a0 * inv); o[1] = (__bf16)(a1 * inv);
    o[2] = (__bf16)(a2 * inv); o[3] = (__bf16)(a3 * inv);
    reinterpret_cast<bf16x4*>(aggb + (size_t)t * 256)[lane] = o;
}

// ---------------------------------------------------------------------------
// fusion + LayerNorm, f32 output. one wave per row; lane owns 4 consecutive cols.
__global__ __launch_bounds__(256) void fuse_ln(const float* __restrict__ x,
                                               const __bf16* __restrict__ aggb,
                                               const __bf16* __restrict__ skipb,
                                               const __bf16* __restrict__ od2b,
                                               const float* __restrict__ wl_p,
                                               const float* __restrict__ wg_p,
                                               const float* __restrict__ gam,
                                               const float* __restrict__ bet,
                                               float* __restrict__ out, int tot) {
    int w = (blockIdx.x * 256 + threadIdx.x) >> 6;
    int lane = threadIdx.x & 63;
    if (w >= tot) return;
    const float wl = wl_p[0], wg = wg_p[0];
    size_t base = (size_t)w * 256;
    float4 xv = reinterpret_cast<const float4*>(x + base)[lane];
    ushort4 ag = reinterpret_cast<const ushort4*>(aggb + base)[lane];
    ushort4 sk = reinterpret_cast<const ushort4*>(skipb + base)[lane];
    ushort4 o2 = reinterpret_cast<const ushort4*>(od2b + base)[lane];
    float v[4];
    v[0] = wl * (us2f(ag.x) + us2f(sk.x)) + wg * (us2f(o2.x) + xv.x) + xv.x;
    v[1] = wl * (us2f(ag.y) + us2f(sk.y)) + wg * (us2f(o2.y) + xv.y) + xv.y;
    v[2] = wl * (us2f(ag.z) + us2f(sk.z)) + wg * (us2f(o2.z) + xv.z) + xv.z;
    v[3] = wl * (us2f(ag.w) + us2f(sk.w)) + wg * (us2f(o2.w) + xv.w) + xv.w;

    float s = v[0] + v[1] + v[2] + v[3];
    #pragma unroll
    for (int off = 32; off; off >>= 1) s += __shfl_xor(s, off);
    float mu = s * (1.0f / 256.0f);
    float e[4], ss = 0.f;
    #pragma unroll
    for (int j = 0; j < 4; ++j) { e[j] = v[j] - mu; ss += e[j] * e[j]; }
    #pragma unroll
    for (int off = 32; off; off >>= 1) ss += __shfl_xor(ss, off);
    float rstd = rsqrtf(ss * (1.0f / 256.0f) + 1e-5f);
    float4 go;
    int c0 = lane * 4;
    go.x = e[0] * rstd * gam[c0 + 0] + bet[c0 + 0];
    go.y = e[1] * rstd * gam[c0 + 1] + bet[c0 + 1];
    go.z = e[2] * rstd * gam[c0 + 2] + bet[c0 + 2];
    go.w = e[3] * rstd * gam[c0 + 3] + bet[c0 + 3];
    reinterpret_cast<float4*>(out + base)[lane] = go;
}

// ---------------------------------------------------------------------------
extern "C" void kernel_launch(void* const* d_in, const int* in_sizes, int n_in,
                              void* d_out, int out_size, void* d_ws, size_t ws_size,
                              hipStream_t stream) {
    const float* x    = (const float*)d_in[0];
    const int*   ei   = (const int*)d_in[1];
    const float* lq_w = (const float*)d_in[3];  const float* lq_b = (const float*)d_in[4];
    const float* lk_w = (const float*)d_in[5];  const float* lk_b = (const float*)d_in[6];
    const float* lv_w = (const float*)d_in[7];  const float* lv_b = (const float*)d_in[8];
    const float* ls_w = (const float*)d_in[9];  const float* ls_b = (const float*)d_in[10];
    const float* gq_w = (const float*)d_in[11]; const float* gq_b = (const float*)d_in[12];
    const float* gk_w = (const float*)d_in[13]; const float* gk_b = (const float*)d_in[14];
    const float* gv_w = (const float*)d_in[15]; const float* gv_b = (const float*)d_in[16];
    const float* go_w = (const float*)d_in[17]; const float* go_b = (const float*)d_in[18];
    const float* wl   = (const float*)d_in[19]; const float* wg   = (const float*)d_in[20];
    const float* ln_g = (const float*)d_in[21]; const float* ln_b = (const float*)d_in[22];

    const int TOT = in_sizes[0] / D_DIM;
    const int E = in_sizes[1] / 2;
    const int B = TOT / NPG;
    const size_t S = (size_t)TOT * D_DIM;

    __bf16* xpk   = (__bf16*)d_ws;
    __bf16* qg    = xpk + S;
    __bf16* kg    = qg + S;
    __bf16* aggb  = kg + S;
    __bf16* ql    = aggb + S;
    __bf16* kl    = ql + S;
    __bf16* vl    = kl + S;
    __bf16* skipb = vl + S;
    __bf16* od2b  = skipb + S;
    __bf16* Vt    = od2b + S;
    __bf16* od    = Vt + S;
    __bf16* wt    = od + S;
    int* bucket = (int*)(wt + 8 * 65536);
    int* deg    = bucket + (size_t)TOT * BCAP;

    // ---- 1. merged prep (pack x, pack W, zero deg) ----
    const int nb1 = TOT / 16;
    const int nbz = (TOT + 255) / 256;
    prep_misc<<<nb1 + 128 + nbz, 256, 0, stream>>>(x, xpk,
        gq_w, gk_w, gv_w, go_w, lq_w, lk_w, lv_w, ls_w, wt, deg, nb1, TOT);

    // ---- 2. fused 7-projection GEMM + edge-bucket build ----
    const int nb_gemm = (TOT / 256) * 28;
    const int nb_edge = (E + 511) / 512;
    proj_csr<<<nb_gemm + nb_edge, 512, 0, stream>>>(xpk, wt,
        gq_b, gk_b, gv_b, lq_b, lk_b, lv_b, ls_b,
        qg, kg, Vt, ql, kl, vl, skipb,
        ei, bucket, deg, E, nb_gemm, TOT);

    // ---- 3. global attention ----
    global_attn_mfma<<<B * HEADS * 4, 256, 0, stream>>>(qg, kg, Vt, od);

    // ---- 4. merged local attention + go GEMM ----
    __bf16* wt_go = wt + 3 * 65536;
    const int nlb = TOT / 4;
    const int nb_go = (TOT / 64) * 4;
    lattn_go<<<nlb + nb_go, 256, 0, stream>>>(ql, kl, vl, bucket, deg, aggb,
                                              od, wt_go, go_b, od2b,
                                              nlb, TOT, TOT);

    // ---- 5. fuse + layernorm -> f32 out ----
    fuse_ln<<<(TOT + 3) / 4, 256, 0, stream>>>(x, aggb, skipb, od2b, wl, wg, ln_g, ln_b,
                                               (float*)d_out, TOT);
}